// Round 7
// baseline (2131.796 us; speedup 1.0000x reference)
//
#include <hip/hip_runtime.h>
#include <hip/hip_bf16.h>
#include <math.h>

#define Bn 4
#define Tn 1024
#define Dn 512
#define Hn 8
#define BHn 32
#define LDP 65   // fp32 LDS stride (pad)
#define LDU 68   // fp32 LDS stride for Ua (16B-aligned rows)
#define LH 72    // fp16 LDS stride in halves

typedef _Float16 f16x8 __attribute__((ext_vector_type(8)));
typedef _Float16 f16x4 __attribute__((ext_vector_type(4)));
typedef float    f32x4 __attribute__((ext_vector_type(4)));

__constant__ float NS_Ac[6] = {3955.0f/1024.0f, 3735.0f/1024.0f, 3799.0f/1024.0f,
                               4019.0f/1024.0f, 2677.0f/1024.0f, 2172.0f/1024.0f};
__constant__ float NS_Bc[6] = {-8306.0f/1024.0f, -6681.0f/1024.0f, -6499.0f/1024.0f,
                               -6385.0f/1024.0f, -3029.0f/1024.0f, -1833.0f/1024.0f};
__constant__ float NS_Cc[6] = {5008.0f/1024.0f, 3463.0f/1024.0f, 3211.0f/1024.0f,
                               2906.0f/1024.0f, 1162.0f/1024.0f,  682.0f/1024.0f};

__device__ __forceinline__ f32x4 mfma16(f16x4 a, f16x4 b, f32x4 c) {
  return __builtin_amdgcn_mfma_f32_16x16x16f16(a, b, c, 0, 0, 0);
}

__device__ __forceinline__ f16x4 cvt4(f32x4 a) {
  f16x4 h;
  h[0] = (_Float16)a[0]; h[1] = (_Float16)a[1];
  h[2] = (_Float16)a[2]; h[3] = (_Float16)a[3];
  return h;
}

__device__ __forceinline__ f16x4 make_If(int r, int g) {
  const int dd = r - 4 * g;
  f16x4 If;
  If[0] = (dd == 0) ? (_Float16)1.f : (_Float16)0.f;
  If[1] = (dd == 1) ? (_Float16)1.f : (_Float16)0.f;
  If[2] = (dd == 2) ? (_Float16)1.f : (_Float16)0.f;
  If[3] = (dd == 3) ? (_Float16)1.f : (_Float16)0.f;
  return If;
}

// ---------- staging helpers ----------

__device__ __forceinline__ void stage_tile_h(_Float16* __restrict__ dst,
                                             const float* __restrict__ src,
                                             int srcStride, int tid) {
#pragma unroll
  for (int i = 0; i < 4; ++i) {
    const int idx = tid + (i << 8);
    const int row = idx >> 4;
    const int c4  = (idx & 15) << 2;
    const float4 v = *reinterpret_cast<const float4*>(src + (size_t)row * srcStride + c4);
    f16x4 h;
    h[0] = (_Float16)v.x; h[1] = (_Float16)v.y; h[2] = (_Float16)v.z; h[3] = (_Float16)v.w;
    *reinterpret_cast<f16x4*>(dst + row * LH + c4) = h;
  }
}

__device__ __forceinline__ void stage_tile_u(float* __restrict__ dst,
                                             const float* __restrict__ src, int tid) {
#pragma unroll
  for (int i = 0; i < 4; ++i) {
    const int idx = tid + (i << 8);
    const int row = idx >> 4;
    const int c4  = (idx & 15) << 2;
    *reinterpret_cast<float4*>(dst + row * LDU + c4) =
        *reinterpret_cast<const float4*>(src + (size_t)row * 64 + c4);
  }
}

__device__ __forceinline__ void tri_solve(const float* __restrict__ Sc,
                                          float* __restrict__ Ua, int tid) {
  if (tid < 64) {
    const int dv = tid;
    for (int r2 = 1; r2 < 64; ++r2) {
      float s = 0.f;
      for (int c = 0; c < r2; ++c) s = fmaf(Sc[r2 * LDP + c], Ua[c * LDU + dv], s);
      Ua[r2 * LDU + dv] -= s;
    }
  }
}

// ---------- kernels ----------

// q/k/v/w projections via fp16 MFMA
__global__ __launch_bounds__(256) void proj4_kernel(
    const float* __restrict__ x,
    const float* __restrict__ W0, const float* __restrict__ W1,
    const float* __restrict__ W2, const float* __restrict__ W3,
    float* __restrict__ o0, float* __restrict__ o1,
    float* __restrict__ o2, float* __restrict__ o3) {
  __shared__ __align__(16) _Float16 Af[64 * LH];
  __shared__ __align__(16) _Float16 Bf[64 * LH];
  const float* W; float* outp;
  switch (blockIdx.z) {
    case 0:  W = W0; outp = o0; break;
    case 1:  W = W1; outp = o1; break;
    case 2:  W = W2; outp = o2; break;
    default: W = W3; outp = o3; break;
  }
  const int tid = threadIdx.x;
  const int m0 = blockIdx.x * 64;
  const int n0 = blockIdx.y * 64;
  const int wid = tid >> 6, lane = tid & 63;
  const int r = lane & 15, g = lane >> 4;
  f32x4 acc[4] = {};
  for (int kt = 0; kt < Dn; kt += 64) {
    stage_tile_h(Af, x + (size_t)m0 * Dn + kt, Dn, tid);
    stage_tile_h(Bf, W + (size_t)n0 * Dn + kt, Dn, tid);
    __syncthreads();
    f16x4 a4[4];
#pragma unroll
    for (int kc = 0; kc < 4; ++kc)
      a4[kc] = *reinterpret_cast<const f16x4*>(Af + (16 * wid + r) * LH + kc * 16 + 4 * g);
#pragma unroll
    for (int jb = 0; jb < 4; ++jb)
#pragma unroll
      for (int kc = 0; kc < 4; ++kc)
        acc[jb] = mfma16(a4[kc],
                         *reinterpret_cast<const f16x4*>(Bf + (16 * jb + r) * LH + kc * 16 + 4 * g),
                         acc[jb]);
    __syncthreads();
  }
#pragma unroll
  for (int jb = 0; jb < 4; ++jb)
#pragma unroll
    for (int d = 0; d < 4; ++d) {
      const int m = m0 + 16 * wid + 4 * g + d;
      const int n = n0 + 16 * jb + r;
      const int b = m >> 10, t = m & 1023, h = n >> 6, e = n & 63;
      outp[(((size_t)(b * Hn + h)) * Tn + t) * 64 + e] = acc[jb][d];
    }
}

// eta/theta projection
#define XSTR 516
__global__ __launch_bounds__(256) void wp_kernel(const float* __restrict__ x,
                                                 const float* __restrict__ Wp,
                                                 float* __restrict__ eta,
                                                 float* __restrict__ theta) {
  __shared__ float xs[16 * XSTR];
  __shared__ float wps[16 * XSTR];
  const int tid = threadIdx.x;
  const int r0 = blockIdx.x * 16;
#pragma unroll
  for (int i = 0; i < 8; ++i) {
    const int idx = tid + (i << 8);
    const int r = idx >> 7, c4 = (idx & 127) << 2;
    const float4 v = *reinterpret_cast<const float4*>(x + (size_t)(r0 + r) * Dn + c4);
    float* p = xs + r * XSTR + c4;
    p[0] = v.x; p[1] = v.y; p[2] = v.z; p[3] = v.w;
    const float4 wv = *reinterpret_cast<const float4*>(Wp + (size_t)r * Dn + c4);
    float* pw = wps + r * XSTR + c4;
    pw[0] = wv.x; pw[1] = wv.y; pw[2] = wv.z; pw[3] = wv.w;
  }
  __syncthreads();
  const int row = tid >> 4, col = tid & 15;
  float acc = 0.f;
#pragma unroll 8
  for (int k = 0; k < Dn; ++k) acc = fmaf(xs[row * XSTR + k], wps[col * XSTR + k], acc);
  const float sg = 1.f / (1.f + __expf(-acc));
  const int m = r0 + row, b = m >> 10, t = m & 1023, h = col >> 1;
  float* dst = (col & 1) ? theta : eta;
  dst[((size_t)(b * Hn + h)) * Tn + t] = sg;
}

// Per-row softmax stats via fp16 MFMA + wave-parallel flash update.
__global__ __launch_bounds__(256) void rowstats_kernel(
    const float* __restrict__ wb, const float* __restrict__ kb,
    float* __restrict__ rowm, float* __restrict__ rowl) {
  __shared__ __align__(16) _Float16 Wh[64 * LH];
  __shared__ __align__(16) _Float16 Kh[64 * LH];
  const int tb = blockIdx.x, bh = blockIdx.y, t0 = tb * 64;
  const int tid = threadIdx.x, wid = tid >> 6, lane = tid & 63;
  const int r = lane & 15, g = lane >> 4;
  stage_tile_h(Wh, wb + ((size_t)bh * Tn + t0) * 64, 64, tid);
  float rm[4], rl[4];
#pragma unroll
  for (int d = 0; d < 4; ++d) { rm[d] = -INFINITY; rl[d] = 0.f; }
  __syncthreads();
  f16x4 wfr[4];
#pragma unroll
  for (int kc = 0; kc < 4; ++kc)
    wfr[kc] = *reinterpret_cast<const f16x4*>(Wh + (16 * wid + r) * LH + kc * 16 + 4 * g);
  for (int sb = 0; sb <= tb; ++sb) {
    __syncthreads();
    stage_tile_h(Kh, kb + ((size_t)bh * Tn + sb * 64) * 64, 64, tid);
    __syncthreads();
    float sv[4][4];
    float tmax[4] = {-INFINITY, -INFINITY, -INFINITY, -INFINITY};
#pragma unroll
    for (int jb = 0; jb < 4; ++jb) {
      f32x4 acc = {0.f, 0.f, 0.f, 0.f};
#pragma unroll
      for (int kc = 0; kc < 4; ++kc)
        acc = mfma16(wfr[kc],
                     *reinterpret_cast<const f16x4*>(Kh + (16 * jb + r) * LH + kc * 16 + 4 * g),
                     acc);
      const int col = sb * 64 + 16 * jb + r;
#pragma unroll
      for (int d = 0; d < 4; ++d) {
        const int row = t0 + 16 * wid + 4 * g + d;
        const float s = (col < row) ? acc[d] * 0.125f : -INFINITY;
        sv[jb][d] = s;
        tmax[d] = fmaxf(tmax[d], s);
      }
    }
#pragma unroll
    for (int m = 1; m < 16; m <<= 1)
#pragma unroll
      for (int d = 0; d < 4; ++d) tmax[d] = fmaxf(tmax[d], __shfl_xor(tmax[d], m, 64));
#pragma unroll
    for (int d = 0; d < 4; ++d) {
      const float mnew  = fmaxf(rm[d], tmax[d]);
      const float msafe = (mnew == -INFINITY) ? 0.f : mnew;
      float s = __expf(sv[0][d] - msafe) + __expf(sv[1][d] - msafe) +
                __expf(sv[2][d] - msafe) + __expf(sv[3][d] - msafe);
#pragma unroll
      for (int m = 1; m < 16; m <<= 1) s += __shfl_xor(s, m, 64);
      const float scale = (rm[d] == -INFINITY) ? 0.f : __expf(rm[d] - msafe);
      rl[d] = rl[d] * scale + s;
      rm[d] = mnew;
    }
  }
  if (r == 0) {
#pragma unroll
    for (int d = 0; d < 4; ++d) {
      const int row = t0 + 16 * wid + 4 * g + d;
      rowm[(size_t)bh * Tn + row] = rm[d];
      rowl[(size_t)bh * Tn + row] = (rl[d] == 0.f) ? 1.f : rl[d];
    }
  }
}

// Ub := vb
__global__ __launch_bounds__(256) void copyU_kernel(const float* __restrict__ vb,
                                                    float* __restrict__ Ub) {
  const int gid = blockIdx.x * 256 + threadIdx.x;
  ((float4*)Ub)[gid] = ((const float4*)vb)[gid];
}

// diagonal solve of block 0
__global__ __launch_bounds__(256) void solve_diag0_kernel(
    const float* __restrict__ wb, const float* __restrict__ kb,
    const float* __restrict__ vb, const float* __restrict__ rowm,
    const float* __restrict__ rowl, float* __restrict__ Ub) {
  __shared__ __align__(16) _Float16 Wh[64 * LH];
  __shared__ __align__(16) _Float16 Kh[64 * LH];
  __shared__ float Sc[64 * LDP];
  __shared__ __align__(16) float Ua[64 * LDU];
  __shared__ float rmL[64], rlL[64];
  const int bh = blockIdx.x;
  const int tid = threadIdx.x, wid = tid >> 6, lane = tid & 63;
  const int r = lane & 15, g = lane >> 4;
  stage_tile_h(Wh, wb + (size_t)bh * Tn * 64, 64, tid);
  stage_tile_h(Kh, kb + (size_t)bh * Tn * 64, 64, tid);
  stage_tile_u(Ua, vb + (size_t)bh * Tn * 64, tid);
  if (tid < 64) { rmL[tid] = rowm[(size_t)bh * Tn + tid]; rlL[tid] = rowl[(size_t)bh * Tn + tid]; }
  __syncthreads();
  f16x4 wfr[4];
#pragma unroll
  for (int kc = 0; kc < 4; ++kc)
    wfr[kc] = *reinterpret_cast<const f16x4*>(Wh + (16 * wid + r) * LH + kc * 16 + 4 * g);
  float rmv[4], rlv[4];
#pragma unroll
  for (int d = 0; d < 4; ++d) {
    rmv[d] = rmL[16 * wid + 4 * g + d];
    rlv[d] = rlL[16 * wid + 4 * g + d];
  }
#pragma unroll
  for (int jb = 0; jb < 4; ++jb) {
    f32x4 acc = {0.f, 0.f, 0.f, 0.f};
#pragma unroll
    for (int kc = 0; kc < 4; ++kc)
      acc = mfma16(wfr[kc],
                   *reinterpret_cast<const f16x4*>(Kh + (16 * jb + r) * LH + kc * 16 + 4 * g),
                   acc);
#pragma unroll
    for (int d = 0; d < 4; ++d) {
      const int lr = 16 * wid + 4 * g + d, lc = 16 * jb + r;
      Sc[lr * LDP + lc] = (lc < lr) ? __expf(acc[d] * 0.125f - rmv[d]) / rlv[d] : 0.f;
    }
  }
  __syncthreads();
  tri_solve(Sc, Ua, tid);
  __syncthreads();
#pragma unroll
  for (int i = 0; i < 4; ++i) {
    const int idx = tid + (i << 8);
    const int row = idx >> 4, c4 = (idx & 15) << 2;
    *reinterpret_cast<float4*>(Ub + ((size_t)bh * Tn + row) * 64 + c4) =
        *reinterpret_cast<const float4*>(Ua + row * LDU + c4);
  }
}

// step ib (MFMA): U[f] -= P[f,ib] @ U[ib]; f==ib+1 also diag-solves
__global__ __launch_bounds__(256) void solve_step_kernel(
    const float* __restrict__ wb, const float* __restrict__ kb,
    const float* __restrict__ rowm, const float* __restrict__ rowl,
    float* __restrict__ Ub, int ib) {
  __shared__ __align__(16) _Float16 Wh[64 * LH];
  __shared__ __align__(16) _Float16 Kh[64 * LH];
  __shared__ __align__(16) _Float16 UTh[64 * LH];
  __shared__ float Sc[64 * LDP];
  __shared__ __align__(16) float Ua[64 * LDU];
  __shared__ float rmL[64], rlL[64];
  const int f = ib + 1 + blockIdx.x, bh = blockIdx.y;
  const int tid = threadIdx.x, wid = tid >> 6, lane = tid & 63;
  const int r = lane & 15, g = lane >> 4;
  stage_tile_h(Wh, wb + ((size_t)bh * Tn + f * 64) * 64, 64, tid);
  stage_tile_h(Kh, kb + ((size_t)bh * Tn + ib * 64) * 64, 64, tid);
  {
    const float* src = Ub + ((size_t)bh * Tn + ib * 64) * 64;
#pragma unroll
    for (int i2 = 0; i2 < 4; ++i2) {
      const int idx = tid + (i2 << 8);
      const int row = idx >> 4, c4 = (idx & 15) << 2;
      const float4 v = *reinterpret_cast<const float4*>(src + (size_t)row * 64 + c4);
      UTh[(c4 + 0) * LH + row] = (_Float16)v.x;
      UTh[(c4 + 1) * LH + row] = (_Float16)v.y;
      UTh[(c4 + 2) * LH + row] = (_Float16)v.z;
      UTh[(c4 + 3) * LH + row] = (_Float16)v.w;
    }
  }
  if (tid < 64) {
    rmL[tid] = rowm[(size_t)bh * Tn + f * 64 + tid];
    rlL[tid] = rowl[(size_t)bh * Tn + f * 64 + tid];
  }
  __syncthreads();
  f16x4 wfr[4];
#pragma unroll
  for (int kc = 0; kc < 4; ++kc)
    wfr[kc] = *reinterpret_cast<const f16x4*>(Wh + (16 * wid + r) * LH + kc * 16 + 4 * g);
  float rmv[4], rlv[4];
#pragma unroll
  for (int d = 0; d < 4; ++d) {
    rmv[d] = rmL[16 * wid + 4 * g + d];
    rlv[d] = rlL[16 * wid + 4 * g + d];
  }
  const f16x4 If = make_If(r, g);
  f16x4 Pfr[4];
#pragma unroll
  for (int jb = 0; jb < 4; ++jb) {
    f32x4 acc = {0.f, 0.f, 0.f, 0.f};
#pragma unroll
    for (int kc = 0; kc < 4; ++kc)
      acc = mfma16(wfr[kc],
                   *reinterpret_cast<const f16x4*>(Kh + (16 * jb + r) * LH + kc * 16 + 4 * g),
                   acc);
    f16x4 pf;
#pragma unroll
    for (int d = 0; d < 4; ++d)
      pf[d] = (_Float16)(-__expf(acc[d] * 0.125f - rmv[d]) / rlv[d]);
    Pfr[jb] = cvt4(mfma16(pf, If, (f32x4){0.f, 0.f, 0.f, 0.f}));
  }
  const float* uf = Ub + ((size_t)bh * Tn + f * 64) * 64;
  f32x4 acc2[4];
#pragma unroll
  for (int i = 0; i < 4; ++i) {
    const float4 v = *reinterpret_cast<const float4*>(uf + (size_t)(16 * wid + r) * 64 + 16 * i + 4 * g);
    acc2[i][0] = v.x; acc2[i][1] = v.y; acc2[i][2] = v.z; acc2[i][3] = v.w;
#pragma unroll
    for (int kc = 0; kc < 4; ++kc)
      acc2[i] = mfma16(*reinterpret_cast<const f16x4*>(UTh + (16 * i + r) * LH + kc * 16 + 4 * g),
                       Pfr[kc], acc2[i]);
  }
  if (f == ib + 1) {
    __syncthreads();
    stage_tile_h(Kh, kb + ((size_t)bh * Tn + f * 64) * 64, 64, tid);
#pragma unroll
    for (int i = 0; i < 4; ++i) {
      float4 v = {acc2[i][0], acc2[i][1], acc2[i][2], acc2[i][3]};
      *reinterpret_cast<float4*>(Ua + (16 * wid + r) * LDU + 16 * i + 4 * g) = v;
    }
    __syncthreads();
#pragma unroll
    for (int jb = 0; jb < 4; ++jb) {
      f32x4 acc = {0.f, 0.f, 0.f, 0.f};
#pragma unroll
      for (int kc = 0; kc < 4; ++kc)
        acc = mfma16(wfr[kc],
                     *reinterpret_cast<const f16x4*>(Kh + (16 * jb + r) * LH + kc * 16 + 4 * g),
                     acc);
#pragma unroll
      for (int d = 0; d < 4; ++d) {
        const int lr = 16 * wid + 4 * g + d, lc = 16 * jb + r;
        Sc[lr * LDP + lc] = (lc < lr) ? __expf(acc[d] * 0.125f - rmv[d]) / rlv[d] : 0.f;
      }
    }
    __syncthreads();
    tri_solve(Sc, Ua, tid);
    __syncthreads();
#pragma unroll
    for (int i2 = 0; i2 < 4; ++i2) {
      const int idx = tid + (i2 << 8);
      const int row = idx >> 4, c4 = (idx & 15) << 2;
      *reinterpret_cast<float4*>(Ub + ((size_t)bh * Tn + f * 64 + row) * 64 + c4) =
          *reinterpret_cast<const float4*>(Ua + row * LDU + c4);
    }
  } else {
#pragma unroll
    for (int i = 0; i < 4; ++i) {
      float4 v = {acc2[i][0], acc2[i][1], acc2[i][2], acc2[i][3]};
      *reinterpret_cast<float4*>(Ub + ((size_t)bh * Tn + f * 64 + 16 * wid + r) * 64 + 16 * i + 4 * g) = v;
    }
  }
}

// Momentum scan: writes fp32 M boundaries every 8 steps (pre-update state)
__global__ __launch_bounds__(256) void mscan_bounds_kernel(
    const float* __restrict__ Ub, const float* __restrict__ kb,
    const float* __restrict__ theta, float* __restrict__ Mcarry,
    float* __restrict__ Mb, int t0, int Tc) {
  const int gid = blockIdx.x * 256 + threadIdx.x;   // BHn*4096
  const int bh = gid >> 12, e = gid & 4095;
  const int dv = e >> 6, dk = e & 63;
  const int nsub8 = Tc >> 3;
  float M = Mcarry[gid];
  const float* Urow = Ub + (size_t)bh * Tn * 64;
  const float* krow = kb + (size_t)bh * Tn * 64;
  const float* th   = theta + (size_t)bh * Tn;
  for (int tl = 0; tl < Tc; ++tl) {
    if ((tl & 7) == 0)
      Mb[((size_t)bh * nsub8 + (tl >> 3)) * 4096 + e] = M;
    const int t = t0 + tl;
    const float thv = th[t];
    const float g = Urow[(size_t)t * 64 + dv] * krow[(size_t)t * 64 + dk];
    M = thv * M + (1.f - thv) * g;
  }
  Mcarry[gid] = M;
}

// Fused: per (bh, 8-step subchunk) block. Each wave regenerates M from the fp32
// boundary (frag positions), runs register NS, accumulates G and o-partials.
// Sp is never written to global.
__global__ __launch_bounds__(256, 2) void ns_fused_kernel(
    const float* __restrict__ Ub, const float* __restrict__ kb,
    const float* __restrict__ qb, const float* __restrict__ eta,
    const float* __restrict__ theta, const float* __restrict__ Mb,
    float* __restrict__ Gbuf, float* __restrict__ opartG,
    int t0, int Tc) {
  __shared__ float uk[512];
  __shared__ float kk[512];
  __shared__ float qs[512];
  __shared__ float th_l[8], et_l[8];
  __shared__ float Gl[64 * 65];
  __shared__ float op[512];
  const int jj = blockIdx.x, bh = blockIdx.y;
  const int nsub8 = Tc >> 3;
  const int tid = threadIdx.x, wid = tid >> 6, lane = tid & 63;
  const int r = lane & 15, g = lane >> 4;
  const int tb = t0 + jj * 8;
  const float* up = Ub + ((size_t)bh * Tn + tb) * 64;
  const float* kp = kb + ((size_t)bh * Tn + tb) * 64;
  const float* qp = qb + ((size_t)bh * Tn + tb) * 64;
#pragma unroll
  for (int i = 0; i < 2; ++i) {
    const int idx = tid + (i << 8);
    uk[idx] = up[idx]; kk[idx] = kp[idx]; qs[idx] = qp[idx];
  }
  if (tid < 8) th_l[tid] = theta[(size_t)bh * Tn + tb + tid];
  else if (tid < 16) et_l[tid - 8] = eta[(size_t)bh * Tn + tb + tid - 8];
#pragma unroll
  for (int i = 0; i < 17; ++i) {
    const int idx = tid + (i << 8);
    if (idx < 64 * 65) Gl[idx] = 0.f;
  }
  op[tid] = 0.f; op[tid + 256] = 0.f;
  __syncthreads();

  const f16x4 If = make_If(r, g);
  float Iw[4];
  Iw[0] = (float)If[0]; Iw[1] = (float)If[1]; Iw[2] = (float)If[2]; Iw[3] = (float)If[3];
  const float* mb = Mb + ((size_t)bh * nsub8 + jj) * 4096;

#pragma unroll 1
  for (int mi = 0; mi < 2; ++mi) {
    const int s = wid * 2 + mi;   // local time step 0..7
    f32x4 acc[4][4];
    // boundary M load in frag positions: element (i*16+r, kc*16+4g+d)
#pragma unroll
    for (int i = 0; i < 4; ++i)
#pragma unroll
      for (int kc = 0; kc < 4; ++kc) {
        const float4 v = *reinterpret_cast<const float4*>(mb + (i * 16 + r) * 64 + kc * 16 + 4 * g);
        acc[i][kc][0] = v.x; acc[i][kc][1] = v.y; acc[i][kc][2] = v.z; acc[i][kc][3] = v.w;
      }
    // momentum recurrence steps 0..s
#pragma unroll 1
    for (int st = 0; st <= s; ++st) {
      const float thv = th_l[st], om = 1.f - thv;
      float omu[4];
#pragma unroll
      for (int i = 0; i < 4; ++i) omu[i] = om * uk[st * 64 + i * 16 + r];
#pragma unroll
      for (int kc = 0; kc < 4; ++kc) {
        const float4 kv = *reinterpret_cast<const float4*>(&kk[st * 64 + kc * 16 + 4 * g]);
        const float kvv[4] = {kv.x, kv.y, kv.z, kv.w};
#pragma unroll
        for (int i = 0; i < 4; ++i)
#pragma unroll
          for (int d = 0; d < 4; ++d)
            acc[i][kc][d] = fmaf(thv, acc[i][kc][d], omu[i] * kvv[d]);
      }
    }
    // Frobenius norm
    float ss = 0.f;
#pragma unroll
    for (int i = 0; i < 4; ++i)
#pragma unroll
      for (int kc = 0; kc < 4; ++kc)
#pragma unroll
        for (int d = 0; d < 4; ++d) ss += acc[i][kc][d] * acc[i][kc][d];
#pragma unroll
    for (int off = 32; off > 0; off >>= 1) ss += __shfl_xor(ss, off, 64);
    const float inv = 1.f / (sqrtf(ss) + 1e-7f);
    f16x4 Xf[4][4];
#pragma unroll
    for (int i = 0; i < 4; ++i)
#pragma unroll
      for (int kc = 0; kc < 4; ++kc) {
        f32x4 sc;
        sc[0] = acc[i][kc][0] * inv; sc[1] = acc[i][kc][1] * inv;
        sc[2] = acc[i][kc][2] * inv; sc[3] = acc[i][kc][3] * inv;
        Xf[i][kc] = cvt4(sc);
      }

    f16x4 Ff[4][4];
#pragma unroll 1
    for (int it = 0; it < 6; ++it) {
      const float ca = NS_Ac[it], cb = NS_Bc[it], cc = NS_Cc[it];
      // m1: acc = X X^T
#pragma unroll
      for (int i = 0; i < 4; ++i)
#pragma unroll
        for (int j = 0; j < 4; ++j) {
          f32x4 a = {0.f, 0.f, 0.f, 0.f};
#pragma unroll
          for (int kc = 0; kc < 4; ++kc) a = mfma16(Xf[i][kc], Xf[j][kc], a);
          acc[i][j] = a;
        }
#pragma unroll
      for (int i = 0; i < 4; ++i)
#pragma unroll
        for (int j = 0; j < 4; ++j) Ff[j][i] = cvt4(acc[i][j]);
      // in-place transpose Xf := X^T
#pragma unroll
      for (int i = 0; i < 4; ++i) {
        {
          const f32x4 t = mfma16(Xf[i][i], If, (f32x4){0.f, 0.f, 0.f, 0.f});
          Xf[i][i] = cvt4(t);
        }
#pragma unroll
        for (int j = i + 1; j < 4; ++j) {
          const f32x4 t1 = mfma16(Xf[i][j], If, (f32x4){0.f, 0.f, 0.f, 0.f});
          const f32x4 t2 = mfma16(Xf[j][i], If, (f32x4){0.f, 0.f, 0.f, 0.f});
          Xf[j][i] = cvt4(t1);
          Xf[i][j] = cvt4(t2);
        }
      }
      // m2: acc = cb A + cc A^2 ; += ca I on diagonal
      const float bc = cb / cc;
#pragma unroll
      for (int i = 0; i < 4; ++i)
#pragma unroll
        for (int j = 0; j < 4; ++j) {
          f32x4 a = acc[i][j];
          a[0] *= bc; a[1] *= bc; a[2] *= bc; a[3] *= bc;
#pragma unroll
          for (int kc = 0; kc < 4; ++kc) a = mfma16(Ff[i][kc], Ff[j][kc], a);
          a[0] *= cc; a[1] *= cc; a[2] *= cc; a[3] *= cc;
          acc[i][j] = a;
        }
#pragma unroll
      for (int i = 0; i < 4; ++i)
#pragma unroll
        for (int d = 0; d < 4; ++d) acc[i][i][d] = fmaf(ca, Iw[d], acc[i][i][d]);
#pragma unroll
      for (int i = 0; i < 4; ++i)
#pragma unroll
        for (int j = 0; j < 4; ++j) Ff[j][i] = cvt4(acc[i][j]);
      // m3: acc = NT(X^T, Bm')  -> fp32 of Sp frag Xf[j][i] is acc[i][j]
#pragma unroll
      for (int i = 0; i < 4; ++i)
#pragma unroll
        for (int j = 0; j < 4; ++j) {
          f32x4 a = {0.f, 0.f, 0.f, 0.f};
#pragma unroll
          for (int kc = 0; kc < 4; ++kc) a = mfma16(Xf[i][kc], Ff[j][kc], a);
          acc[i][j] = a;
        }
      if (it < 5) {
#pragma unroll
        for (int i = 0; i < 4; ++i)
#pragma unroll
          for (int j = 0; j < 4; ++j) Xf[j][i] = cvt4(acc[i][j]);
      }
    }
    // Sp fp32 value at (row = i2*16+r, col = kc2*16+4g+d) is acc[kc2][i2][d]
    const float ev = et_l[s];
    // G += eta * Sp  (LDS atomics, pad-65)
#pragma unroll
    for (int i2 = 0; i2 < 4; ++i2)
#pragma unroll
      for (int kc2 = 0; kc2 < 4; ++kc2)
#pragma unroll
        for (int d = 0; d < 4; ++d)
          atomicAdd(&Gl[(i2 * 16 + r) * 65 + kc2 * 16 + 4 * g + d], ev * acc[kc2][i2][d]);
    // o-partials: for t >= s: op[t][row] += eta_s * (Sp_s q_t)[row]
#pragma unroll 1
    for (int t = s; t < 8; ++t) {
      float pr[4] = {0.f, 0.f, 0.f, 0.f};
#pragma unroll
      for (int kc2 = 0; kc2 < 4; ++kc2) {
        const float4 qv = *reinterpret_cast<const float4*>(&qs[t * 64 + kc2 * 16 + 4 * g]);
        const float qvv[4] = {qv.x, qv.y, qv.z, qv.w};
#pragma unroll
        for (int i2 = 0; i2 < 4; ++i2)
#pragma unroll
          for (int d = 0; d < 4; ++d)
            pr[i2] = fmaf(acc[kc2][i2][d], qvv[d], pr[i2]);
      }
#pragma unroll
      for (int i2 = 0; i2 < 4; ++i2) {
        pr[i2] += __shfl_xor(pr[i2], 16, 64);
        pr[i2] += __shfl_xor(pr[i2], 32, 64);
      }
      if (g == 0) {
#pragma unroll
        for (int i2 = 0; i2 < 4; ++i2)
          atomicAdd(&op[t * 64 + i2 * 16 + r], ev * pr[i2]);
      }
    }
  }
  __syncthreads();
  float* gout = Gbuf + ((size_t)bh * nsub8 + jj) * 4096;
#pragma unroll
  for (int i = 0; i < 16; ++i) {
    const int idx = tid + (i << 8);
    gout[idx] = Gl[(idx >> 6) * 65 + (idx & 63)];
  }
  float* oout = opartG + ((size_t)bh * Tc + jj * 8) * 64;
  oout[tid] = op[tid];
  oout[tid + 256] = op[tid + 256];
}

// scan G over 8-step subchunks -> Sbase; updates Scarry
__global__ __launch_bounds__(256) void sbase_kernel(
    float* __restrict__ Scarry, const float* __restrict__ Gbuf,
    float* __restrict__ Sbase, int Tc) {
  const int gid = blockIdx.x * 256 + threadIdx.x;   // BHn*4096
  const int bh = gid >> 12, e = gid & 4095;
  const int nsub8 = Tc >> 3;
  float S = Scarry[gid];
  for (int j = 0; j < nsub8; ++j) {
    const size_t idx = ((size_t)bh * nsub8 + j) * 4096 + e;
    Sbase[idx] = S;
    S += Gbuf[idx];
  }
  Scarry[gid] = S;
}

// o_t = Sbase_j q_t + opart_t ; 8 independent matvecs per block
__global__ __launch_bounds__(256) void outv3_kernel(
    const float* __restrict__ qb, const float* __restrict__ Sbase,
    const float* __restrict__ opartG, float* __restrict__ ob, int t0, int Tc) {
  const int jj = blockIdx.x, bh = blockIdx.y, tid = threadIdx.x;
  const int nsub8 = Tc >> 3;
  const int ty = tid >> 4, tx = tid & 15;
  const int dv0 = ty * 4, dk0 = tx * 4;
  float S[4][4];
  const float* sb = Sbase + ((size_t)bh * nsub8 + jj) * 4096;
#pragma unroll
  for (int r2 = 0; r2 < 4; ++r2) {
    const float4 v = *reinterpret_cast<const float4*>(sb + (dv0 + r2) * 64 + dk0);
    S[r2][0] = v.x; S[r2][1] = v.y; S[r2][2] = v.z; S[r2][3] = v.w;
  }
#pragma unroll
  for (int i = 0; i < 8; ++i) {
    const int t = t0 + jj * 8 + i;
    const float4 q4 = *reinterpret_cast<const float4*>(qb + ((size_t)bh * Tn + t) * 64 + dk0);
    float part[4];
#pragma unroll
    for (int r2 = 0; r2 < 4; ++r2)
      part[r2] = S[r2][0] * q4.x + S[r2][1] * q4.y + S[r2][2] * q4.z + S[r2][3] * q4.w;
#pragma unroll
    for (int m = 1; m < 16; m <<= 1)
#pragma unroll
      for (int r2 = 0; r2 < 4; ++r2) part[r2] += __shfl_xor(part[r2], m, 64);
    if (tx == 0) {
      const float4 opv = *reinterpret_cast<const float4*>(
          opartG + ((size_t)bh * Tc + jj * 8 + i) * 64 + dv0);
      float4 o4 = {part[0] + opv.x, part[1] + opv.y, part[2] + opv.z, part[3] + opv.w};
      *reinterpret_cast<float4*>(ob + ((size_t)bh * Tn + t) * 64 + dv0) = o4;
    }
  }
}

// init carries
__global__ __launch_bounds__(256) void init_carry_kernel(
    const float* __restrict__ S0, const float* __restrict__ M0,
    float* __restrict__ Scarry, float* __restrict__ Mcarry) {
  const int gid = blockIdx.x * 256 + threadIdx.x;
  const int h = (gid >> 12) & 7, e = gid & 4095;
  Scarry[gid] = S0[h * 4096 + e];
  Mcarry[gid] = M0[h * 4096 + e];
}

// final: out = o_flat @ Wo^T via fp16 MFMA
__global__ __launch_bounds__(256) void out_gemm_kernel(
    const float* __restrict__ ob, const float* __restrict__ Wo,
    float* __restrict__ out) {
  __shared__ __align__(16) _Float16 Af[64 * LH];
  __shared__ __align__(16) _Float16 Bf[64 * LH];
  const int tid = threadIdx.x;
  const int m0 = blockIdx.x * 64;
  const int n0 = blockIdx.y * 64;
  const int wid = tid >> 6, lane = tid & 63;
  const int r = lane & 15, g = lane >> 4;
  f32x4 acc[4] = {};
  for (int kt = 0; kt < Dn; kt += 64) {
    const int h = kt >> 6;
#pragma unroll
    for (int i = 0; i < 4; ++i) {
      const int idx = tid + (i << 8);
      const int row = idx >> 4, c4 = (idx & 15) << 2;
      const int m = m0 + row, b = m >> 10, t = m & 1023;
      const float4 v = *reinterpret_cast<const float4*>(
          ob + ((size_t)(b * Hn + h) * Tn + t) * 64 + c4);
      f16x4 hv;
      hv[0] = (_Float16)v.x; hv[1] = (_Float16)v.y; hv[2] = (_Float16)v.z; hv[3] = (_Float16)v.w;
      *reinterpret_cast<f16x4*>(Af + row * LH + c4) = hv;
    }
    stage_tile_h(Bf, Wo + (size_t)n0 * Dn + kt, Dn, tid);
    __syncthreads();
    f16x4 a4[4];
#pragma unroll
    for (int kc = 0; kc < 4; ++kc)
      a4[kc] = *reinterpret_cast<const f16x4*>(Af + (16 * wid + r) * LH + kc * 16 + 4 * g);
#pragma unroll
    for (int jb = 0; jb < 4; ++jb)
#pragma unroll
      for (int kc = 0; kc < 4; ++kc)
        acc[jb] = mfma16(a4[kc],
                         *reinterpret_cast<const f16x4*>(Bf + (16 * jb + r) * LH + kc * 16 + 4 * g),
                         acc[jb]);
    __syncthreads();
  }
#pragma unroll
  for (int jb = 0; jb < 4; ++jb)
#pragma unroll
    for (int d = 0; d < 4; ++d) {
      const int m = m0 + 16 * wid + 4 * g + d;
      const int n = n0 + 16 * jb + r;
      out[(size_t)m * Dn + n] = acc[jb][d];
    }
}

// ---------- host ----------

extern "C" void kernel_launch(void* const* d_in, const int* in_sizes, int n_in,
                              void* d_out, int out_size, void* d_ws, size_t ws_size,
                              hipStream_t stream) {
  (void)in_sizes; (void)n_in; (void)out_size;
  const float* x  = (const float*)d_in[0];
  const float* Wq = (const float*)d_in[1];
  const float* Wk = (const float*)d_in[2];
  const float* Wv = (const float*)d_in[3];
  const float* Ww = (const float*)d_in[4];
  const float* Wp = (const float*)d_in[5];
  const float* Wo = (const float*)d_in[6];
  const float* S0 = (const float*)d_in[7];
  const float* M0 = (const float*)d_in[8];
  float* out = (float*)d_out;
  float* ws  = (float*)d_ws;

  size_t off = 0;
  float* qb  = ws + off; off += (size_t)BHn * Tn * 64;
  float* kb  = ws + off; off += (size_t)BHn * Tn * 64;
  float* vb  = ws + off; off += (size_t)BHn * Tn * 64;
  float* wb  = ws + off; off += (size_t)BHn * Tn * 64;
  float* Ub  = ws + off; off += (size_t)BHn * Tn * 64;
  float* ob  = ws + off; off += (size_t)BHn * Tn * 64;
  float* eta   = ws + off; off += (size_t)BHn * Tn;
  float* theta = ws + off; off += (size_t)BHn * Tn;
  float* rowm  = ws + off; off += (size_t)BHn * Tn;
  float* rowl  = ws + off; off += (size_t)BHn * Tn;
  float* Mcarry = ws + off; off += (size_t)BHn * 4096;
  float* Scarry = ws + off; off += (size_t)BHn * 4096;

  const size_t avail0 = ws_size / sizeof(float) - off;
  int Tc = 256;
  // need: Mb + Gbuf + Sbase (3 * BHn*(Tc/8)*4096) + opartG (BHn*Tc*64)
  while (Tc > 16 &&
         3 * (size_t)BHn * (Tc / 8) * 4096 + (size_t)BHn * Tc * 64 > avail0)
    Tc >>= 1;
  const int nsub8 = Tc >> 3;

  float* Mb     = ws + off; off += (size_t)BHn * nsub8 * 4096;
  float* Gbuf   = ws + off; off += (size_t)BHn * nsub8 * 4096;
  float* Sbase  = ws + off; off += (size_t)BHn * nsub8 * 4096;
  float* opartG = ws + off; off += (size_t)BHn * Tc * 64;

  hipLaunchKernelGGL(init_carry_kernel, dim3(512), dim3(256), 0, stream, S0, M0, Scarry, Mcarry);
  hipLaunchKernelGGL(proj4_kernel, dim3(64, 8, 4), dim3(256), 0, stream,
                     x, Wq, Wk, Wv, Ww, qb, kb, vb, wb);
  hipLaunchKernelGGL(wp_kernel, dim3(256), dim3(256), 0, stream, x, Wp, eta, theta);
  hipLaunchKernelGGL(rowstats_kernel, dim3(16, 32), dim3(256), 0, stream, wb, kb, rowm, rowl);
  hipLaunchKernelGGL(copyU_kernel, dim3(2048), dim3(256), 0, stream, vb, Ub);
  hipLaunchKernelGGL(solve_diag0_kernel, dim3(32), dim3(256), 0, stream,
                     wb, kb, vb, rowm, rowl, Ub);
  for (int ib = 0; ib < 15; ++ib) {
    hipLaunchKernelGGL(solve_step_kernel, dim3(15 - ib, 32), dim3(256), 0, stream,
                       wb, kb, rowm, rowl, Ub, ib);
  }

  for (int t0 = 0; t0 < Tn; t0 += Tc) {
    hipLaunchKernelGGL(mscan_bounds_kernel, dim3(512), dim3(256), 0, stream,
                       Ub, kb, theta, Mcarry, Mb, t0, Tc);
    hipLaunchKernelGGL(ns_fused_kernel, dim3(nsub8, BHn), dim3(256), 0, stream,
                       Ub, kb, qb, eta, theta, Mb, Gbuf, opartG, t0, Tc);
    hipLaunchKernelGGL(sbase_kernel, dim3(512), dim3(256), 0, stream, Scarry, Gbuf, Sbase, Tc);
    hipLaunchKernelGGL(outv3_kernel, dim3(nsub8, BHn), dim3(256), 0, stream,
                       qb, Sbase, opartG, ob, t0, Tc);
  }

  hipLaunchKernelGGL(out_gemm_kernel, dim3(64, 8), dim3(256), 0, stream, ob, Wo, out);
}

// Round 8
// 1387.927 us; speedup vs baseline: 1.5360x; 1.5360x over previous
//
#include <hip/hip_runtime.h>
#include <hip/hip_bf16.h>
#include <math.h>

#define Bn 4
#define Tn 1024
#define Dn 512
#define Hn 8
#define BHn 32
#define LDP 65   // fp32 LDS stride (pad)
#define LDU 68   // fp32 LDS stride for Ua (16B-aligned rows)
#define LH 72    // fp16 LDS stride in halves

typedef _Float16 f16x8 __attribute__((ext_vector_type(8)));
typedef _Float16 f16x4 __attribute__((ext_vector_type(4)));
typedef float    f32x4 __attribute__((ext_vector_type(4)));

__constant__ float NS_Ac[6] = {3955.0f/1024.0f, 3735.0f/1024.0f, 3799.0f/1024.0f,
                               4019.0f/1024.0f, 2677.0f/1024.0f, 2172.0f/1024.0f};
__constant__ float NS_Bc[6] = {-8306.0f/1024.0f, -6681.0f/1024.0f, -6499.0f/1024.0f,
                               -6385.0f/1024.0f, -3029.0f/1024.0f, -1833.0f/1024.0f};
__constant__ float NS_Cc[6] = {5008.0f/1024.0f, 3463.0f/1024.0f, 3211.0f/1024.0f,
                               2906.0f/1024.0f, 1162.0f/1024.0f,  682.0f/1024.0f};

__device__ __forceinline__ f32x4 mfma16(f16x4 a, f16x4 b, f32x4 c) {
  return __builtin_amdgcn_mfma_f32_16x16x16f16(a, b, c, 0, 0, 0);
}

__device__ __forceinline__ f16x4 cvt4(f32x4 a) {
  f16x4 h;
  h[0] = (_Float16)a[0]; h[1] = (_Float16)a[1];
  h[2] = (_Float16)a[2]; h[3] = (_Float16)a[3];
  return h;
}

__device__ __forceinline__ f16x4 make_If(int r, int g) {
  const int dd = r - 4 * g;
  f16x4 If;
  If[0] = (dd == 0) ? (_Float16)1.f : (_Float16)0.f;
  If[1] = (dd == 1) ? (_Float16)1.f : (_Float16)0.f;
  If[2] = (dd == 2) ? (_Float16)1.f : (_Float16)0.f;
  If[3] = (dd == 3) ? (_Float16)1.f : (_Float16)0.f;
  return If;
}

// ---------- staging helpers ----------

__device__ __forceinline__ void stage_tile_h(_Float16* __restrict__ dst,
                                             const float* __restrict__ src,
                                             int srcStride, int tid) {
#pragma unroll
  for (int i = 0; i < 4; ++i) {
    const int idx = tid + (i << 8);
    const int row = idx >> 4;
    const int c4  = (idx & 15) << 2;
    const float4 v = *reinterpret_cast<const float4*>(src + (size_t)row * srcStride + c4);
    f16x4 h;
    h[0] = (_Float16)v.x; h[1] = (_Float16)v.y; h[2] = (_Float16)v.z; h[3] = (_Float16)v.w;
    *reinterpret_cast<f16x4*>(dst + row * LH + c4) = h;
  }
}

__device__ __forceinline__ void stage_tile_u(float* __restrict__ dst,
                                             const float* __restrict__ src, int tid) {
#pragma unroll
  for (int i = 0; i < 4; ++i) {
    const int idx = tid + (i << 8);
    const int row = idx >> 4;
    const int c4  = (idx & 15) << 2;
    *reinterpret_cast<float4*>(dst + row * LDU + c4) =
        *reinterpret_cast<const float4*>(src + (size_t)row * 64 + c4);
  }
}

// Blocked unit-lower-triangular solve: 16-row diagonal triangles (wave 0)
// + block-parallel rank-16 updates (all 256 threads). Sc strict-lower [64][LDP].
__device__ __forceinline__ void tri_solve_blocked(const float* __restrict__ Sc,
                                                  float* __restrict__ Ua, int tid) {
  const int dv = tid & 63;
  const int grp = tid >> 6;
#pragma unroll 1
  for (int db = 0; db < 4; ++db) {
    const int base = db * 16;
    if (grp == 0) {               // 16x16 triangle, rows depend sequentially
#pragma unroll 1
      for (int rr = 1; rr < 16; ++rr) {
        float s = 0.f;
        for (int c = 0; c < rr; ++c)
          s = fmaf(Sc[(base + rr) * LDP + base + c], Ua[(base + c) * LDU + dv], s);
        Ua[(base + rr) * LDU + dv] -= s;
      }
    }
    __syncthreads();
    if (db < 3) {                 // rank-16 update of all rows below
      for (int r2 = base + 16 + grp; r2 < 64; r2 += 4) {
        float s = 0.f;
#pragma unroll
        for (int c = 0; c < 16; ++c)
          s = fmaf(Sc[r2 * LDP + base + c], Ua[(base + c) * LDU + dv], s);
        Ua[r2 * LDU + dv] -= s;
      }
    }
    __syncthreads();
  }
}

// ---------- kernels ----------

// q/k/v/w projections via fp16 MFMA
__global__ __launch_bounds__(256) void proj4_kernel(
    const float* __restrict__ x,
    const float* __restrict__ W0, const float* __restrict__ W1,
    const float* __restrict__ W2, const float* __restrict__ W3,
    float* __restrict__ o0, float* __restrict__ o1,
    float* __restrict__ o2, float* __restrict__ o3) {
  __shared__ __align__(16) _Float16 Af[64 * LH];
  __shared__ __align__(16) _Float16 Bf[64 * LH];
  const float* W; float* outp;
  switch (blockIdx.z) {
    case 0:  W = W0; outp = o0; break;
    case 1:  W = W1; outp = o1; break;
    case 2:  W = W2; outp = o2; break;
    default: W = W3; outp = o3; break;
  }
  const int tid = threadIdx.x;
  const int m0 = blockIdx.x * 64;
  const int n0 = blockIdx.y * 64;
  const int wid = tid >> 6, lane = tid & 63;
  const int r = lane & 15, g = lane >> 4;
  f32x4 acc[4] = {};
  for (int kt = 0; kt < Dn; kt += 64) {
    stage_tile_h(Af, x + (size_t)m0 * Dn + kt, Dn, tid);
    stage_tile_h(Bf, W + (size_t)n0 * Dn + kt, Dn, tid);
    __syncthreads();
    f16x4 a4[4];
#pragma unroll
    for (int kc = 0; kc < 4; ++kc)
      a4[kc] = *reinterpret_cast<const f16x4*>(Af + (16 * wid + r) * LH + kc * 16 + 4 * g);
#pragma unroll
    for (int jb = 0; jb < 4; ++jb)
#pragma unroll
      for (int kc = 0; kc < 4; ++kc)
        acc[jb] = mfma16(a4[kc],
                         *reinterpret_cast<const f16x4*>(Bf + (16 * jb + r) * LH + kc * 16 + 4 * g),
                         acc[jb]);
    __syncthreads();
  }
#pragma unroll
  for (int jb = 0; jb < 4; ++jb)
#pragma unroll
    for (int d = 0; d < 4; ++d) {
      const int m = m0 + 16 * wid + 4 * g + d;
      const int n = n0 + 16 * jb + r;
      const int b = m >> 10, t = m & 1023, h = n >> 6, e = n & 63;
      outp[(((size_t)(b * Hn + h)) * Tn + t) * 64 + e] = acc[jb][d];
    }
}

// eta/theta projection
#define XSTR 516
__global__ __launch_bounds__(256) void wp_kernel(const float* __restrict__ x,
                                                 const float* __restrict__ Wp,
                                                 float* __restrict__ eta,
                                                 float* __restrict__ theta) {
  __shared__ float xs[16 * XSTR];
  __shared__ float wps[16 * XSTR];
  const int tid = threadIdx.x;
  const int r0 = blockIdx.x * 16;
#pragma unroll
  for (int i = 0; i < 8; ++i) {
    const int idx = tid + (i << 8);
    const int r = idx >> 7, c4 = (idx & 127) << 2;
    const float4 v = *reinterpret_cast<const float4*>(x + (size_t)(r0 + r) * Dn + c4);
    float* p = xs + r * XSTR + c4;
    p[0] = v.x; p[1] = v.y; p[2] = v.z; p[3] = v.w;
    const float4 wv = *reinterpret_cast<const float4*>(Wp + (size_t)r * Dn + c4);
    float* pw = wps + r * XSTR + c4;
    pw[0] = wv.x; pw[1] = wv.y; pw[2] = wv.z; pw[3] = wv.w;
  }
  __syncthreads();
  const int row = tid >> 4, col = tid & 15;
  float acc = 0.f;
#pragma unroll 8
  for (int k = 0; k < Dn; ++k) acc = fmaf(xs[row * XSTR + k], wps[col * XSTR + k], acc);
  const float sg = 1.f / (1.f + __expf(-acc));
  const int m = r0 + row, b = m >> 10, t = m & 1023, h = col >> 1;
  float* dst = (col & 1) ? theta : eta;
  dst[((size_t)(b * Hn + h)) * Tn + t] = sg;
}

// Per-row softmax stats via fp16 MFMA + wave-parallel flash update.
__global__ __launch_bounds__(256) void rowstats_kernel(
    const float* __restrict__ wb, const float* __restrict__ kb,
    float* __restrict__ rowm, float* __restrict__ rowl) {
  __shared__ __align__(16) _Float16 Wh[64 * LH];
  __shared__ __align__(16) _Float16 Kh[64 * LH];
  const int tb = blockIdx.x, bh = blockIdx.y, t0 = tb * 64;
  const int tid = threadIdx.x, wid = tid >> 6, lane = tid & 63;
  const int r = lane & 15, g = lane >> 4;
  stage_tile_h(Wh, wb + ((size_t)bh * Tn + t0) * 64, 64, tid);
  float rm[4], rl[4];
#pragma unroll
  for (int d = 0; d < 4; ++d) { rm[d] = -INFINITY; rl[d] = 0.f; }
  __syncthreads();
  f16x4 wfr[4];
#pragma unroll
  for (int kc = 0; kc < 4; ++kc)
    wfr[kc] = *reinterpret_cast<const f16x4*>(Wh + (16 * wid + r) * LH + kc * 16 + 4 * g);
  for (int sb = 0; sb <= tb; ++sb) {
    __syncthreads();
    stage_tile_h(Kh, kb + ((size_t)bh * Tn + sb * 64) * 64, 64, tid);
    __syncthreads();
    float sv[4][4];
    float tmax[4] = {-INFINITY, -INFINITY, -INFINITY, -INFINITY};
#pragma unroll
    for (int jb = 0; jb < 4; ++jb) {
      f32x4 acc = {0.f, 0.f, 0.f, 0.f};
#pragma unroll
      for (int kc = 0; kc < 4; ++kc)
        acc = mfma16(wfr[kc],
                     *reinterpret_cast<const f16x4*>(Kh + (16 * jb + r) * LH + kc * 16 + 4 * g),
                     acc);
      const int col = sb * 64 + 16 * jb + r;
#pragma unroll
      for (int d = 0; d < 4; ++d) {
        const int row = t0 + 16 * wid + 4 * g + d;
        const float s = (col < row) ? acc[d] * 0.125f : -INFINITY;
        sv[jb][d] = s;
        tmax[d] = fmaxf(tmax[d], s);
      }
    }
#pragma unroll
    for (int m = 1; m < 16; m <<= 1)
#pragma unroll
      for (int d = 0; d < 4; ++d) tmax[d] = fmaxf(tmax[d], __shfl_xor(tmax[d], m, 64));
#pragma unroll
    for (int d = 0; d < 4; ++d) {
      const float mnew  = fmaxf(rm[d], tmax[d]);
      const float msafe = (mnew == -INFINITY) ? 0.f : mnew;
      float s = __expf(sv[0][d] - msafe) + __expf(sv[1][d] - msafe) +
                __expf(sv[2][d] - msafe) + __expf(sv[3][d] - msafe);
#pragma unroll
      for (int m = 1; m < 16; m <<= 1) s += __shfl_xor(s, m, 64);
      const float scale = (rm[d] == -INFINITY) ? 0.f : __expf(rm[d] - msafe);
      rl[d] = rl[d] * scale + s;
      rm[d] = mnew;
    }
  }
  if (r == 0) {
#pragma unroll
    for (int d = 0; d < 4; ++d) {
      const int row = t0 + 16 * wid + 4 * g + d;
      rowm[(size_t)bh * Tn + row] = rm[d];
      rowl[(size_t)bh * Tn + row] = (rl[d] == 0.f) ? 1.f : rl[d];
    }
  }
}

// Ub := vb
__global__ __launch_bounds__(256) void copyU_kernel(const float* __restrict__ vb,
                                                    float* __restrict__ Ub) {
  const int gid = blockIdx.x * 256 + threadIdx.x;
  ((float4*)Ub)[gid] = ((const float4*)vb)[gid];
}

// diagonal solve of block 0
__global__ __launch_bounds__(256) void solve_diag0_kernel(
    const float* __restrict__ wb, const float* __restrict__ kb,
    const float* __restrict__ vb, const float* __restrict__ rowm,
    const float* __restrict__ rowl, float* __restrict__ Ub) {
  __shared__ __align__(16) _Float16 Wh[64 * LH];
  __shared__ __align__(16) _Float16 Kh[64 * LH];
  __shared__ float Sc[64 * LDP];
  __shared__ __align__(16) float Ua[64 * LDU];
  __shared__ float rmL[64], rlL[64];
  const int bh = blockIdx.x;
  const int tid = threadIdx.x, wid = tid >> 6, lane = tid & 63;
  const int r = lane & 15, g = lane >> 4;
  stage_tile_h(Wh, wb + (size_t)bh * Tn * 64, 64, tid);
  stage_tile_h(Kh, kb + (size_t)bh * Tn * 64, 64, tid);
  stage_tile_u(Ua, vb + (size_t)bh * Tn * 64, tid);
  if (tid < 64) { rmL[tid] = rowm[(size_t)bh * Tn + tid]; rlL[tid] = rowl[(size_t)bh * Tn + tid]; }
  __syncthreads();
  f16x4 wfr[4];
#pragma unroll
  for (int kc = 0; kc < 4; ++kc)
    wfr[kc] = *reinterpret_cast<const f16x4*>(Wh + (16 * wid + r) * LH + kc * 16 + 4 * g);
  float rmv[4], rlv[4];
#pragma unroll
  for (int d = 0; d < 4; ++d) {
    rmv[d] = rmL[16 * wid + 4 * g + d];
    rlv[d] = rlL[16 * wid + 4 * g + d];
  }
#pragma unroll
  for (int jb = 0; jb < 4; ++jb) {
    f32x4 acc = {0.f, 0.f, 0.f, 0.f};
#pragma unroll
    for (int kc = 0; kc < 4; ++kc)
      acc = mfma16(wfr[kc],
                   *reinterpret_cast<const f16x4*>(Kh + (16 * jb + r) * LH + kc * 16 + 4 * g),
                   acc);
#pragma unroll
    for (int d = 0; d < 4; ++d) {
      const int lr = 16 * wid + 4 * g + d, lc = 16 * jb + r;
      Sc[lr * LDP + lc] = (lc < lr) ? __expf(acc[d] * 0.125f - rmv[d]) / rlv[d] : 0.f;
    }
  }
  __syncthreads();
  tri_solve_blocked(Sc, Ua, tid);
#pragma unroll
  for (int i = 0; i < 4; ++i) {
    const int idx = tid + (i << 8);
    const int row = idx >> 4, c4 = (idx & 15) << 2;
    *reinterpret_cast<float4*>(Ub + ((size_t)bh * Tn + row) * 64 + c4) =
        *reinterpret_cast<const float4*>(Ua + row * LDU + c4);
  }
}

// step ib (MFMA): U[f] -= P[f,ib] @ U[ib]; f==ib+1 also diag-solves
__global__ __launch_bounds__(256) void solve_step_kernel(
    const float* __restrict__ wb, const float* __restrict__ kb,
    const float* __restrict__ rowm, const float* __restrict__ rowl,
    float* __restrict__ Ub, int ib) {
  __shared__ __align__(16) _Float16 Wh[64 * LH];
  __shared__ __align__(16) _Float16 Kh[64 * LH];
  __shared__ __align__(16) _Float16 UTh[64 * LH];
  __shared__ float Sc[64 * LDP];
  __shared__ __align__(16) float Ua[64 * LDU];
  __shared__ float rmL[64], rlL[64];
  const int f = ib + 1 + blockIdx.x, bh = blockIdx.y;
  const int tid = threadIdx.x, wid = tid >> 6, lane = tid & 63;
  const int r = lane & 15, g = lane >> 4;
  stage_tile_h(Wh, wb + ((size_t)bh * Tn + f * 64) * 64, 64, tid);
  stage_tile_h(Kh, kb + ((size_t)bh * Tn + ib * 64) * 64, 64, tid);
  {
    const float* src = Ub + ((size_t)bh * Tn + ib * 64) * 64;
#pragma unroll
    for (int i2 = 0; i2 < 4; ++i2) {
      const int idx = tid + (i2 << 8);
      const int row = idx >> 4, c4 = (idx & 15) << 2;
      const float4 v = *reinterpret_cast<const float4*>(src + (size_t)row * 64 + c4);
      UTh[(c4 + 0) * LH + row] = (_Float16)v.x;
      UTh[(c4 + 1) * LH + row] = (_Float16)v.y;
      UTh[(c4 + 2) * LH + row] = (_Float16)v.z;
      UTh[(c4 + 3) * LH + row] = (_Float16)v.w;
    }
  }
  if (tid < 64) {
    rmL[tid] = rowm[(size_t)bh * Tn + f * 64 + tid];
    rlL[tid] = rowl[(size_t)bh * Tn + f * 64 + tid];
  }
  __syncthreads();
  f16x4 wfr[4];
#pragma unroll
  for (int kc = 0; kc < 4; ++kc)
    wfr[kc] = *reinterpret_cast<const f16x4*>(Wh + (16 * wid + r) * LH + kc * 16 + 4 * g);
  float rmv[4], rlv[4];
#pragma unroll
  for (int d = 0; d < 4; ++d) {
    rmv[d] = rmL[16 * wid + 4 * g + d];
    rlv[d] = rlL[16 * wid + 4 * g + d];
  }
  const f16x4 If = make_If(r, g);
  f16x4 Pfr[4];
#pragma unroll
  for (int jb = 0; jb < 4; ++jb) {
    f32x4 acc = {0.f, 0.f, 0.f, 0.f};
#pragma unroll
    for (int kc = 0; kc < 4; ++kc)
      acc = mfma16(wfr[kc],
                   *reinterpret_cast<const f16x4*>(Kh + (16 * jb + r) * LH + kc * 16 + 4 * g),
                   acc);
    f16x4 pf;
#pragma unroll
    for (int d = 0; d < 4; ++d)
      pf[d] = (_Float16)(-__expf(acc[d] * 0.125f - rmv[d]) / rlv[d]);
    Pfr[jb] = cvt4(mfma16(pf, If, (f32x4){0.f, 0.f, 0.f, 0.f}));
  }
  const float* uf = Ub + ((size_t)bh * Tn + f * 64) * 64;
  f32x4 acc2[4];
#pragma unroll
  for (int i = 0; i < 4; ++i) {
    const float4 v = *reinterpret_cast<const float4*>(uf + (size_t)(16 * wid + r) * 64 + 16 * i + 4 * g);
    acc2[i][0] = v.x; acc2[i][1] = v.y; acc2[i][2] = v.z; acc2[i][3] = v.w;
#pragma unroll
    for (int kc = 0; kc < 4; ++kc)
      acc2[i] = mfma16(*reinterpret_cast<const f16x4*>(UTh + (16 * i + r) * LH + kc * 16 + 4 * g),
                       Pfr[kc], acc2[i]);
  }
  if (f == ib + 1) {
    __syncthreads();
    stage_tile_h(Kh, kb + ((size_t)bh * Tn + f * 64) * 64, 64, tid);
#pragma unroll
    for (int i = 0; i < 4; ++i) {
      float4 v = {acc2[i][0], acc2[i][1], acc2[i][2], acc2[i][3]};
      *reinterpret_cast<float4*>(Ua + (16 * wid + r) * LDU + 16 * i + 4 * g) = v;
    }
    __syncthreads();
#pragma unroll
    for (int jb = 0; jb < 4; ++jb) {
      f32x4 acc = {0.f, 0.f, 0.f, 0.f};
#pragma unroll
      for (int kc = 0; kc < 4; ++kc)
        acc = mfma16(wfr[kc],
                     *reinterpret_cast<const f16x4*>(Kh + (16 * jb + r) * LH + kc * 16 + 4 * g),
                     acc);
#pragma unroll
      for (int d = 0; d < 4; ++d) {
        const int lr = 16 * wid + 4 * g + d, lc = 16 * jb + r;
        Sc[lr * LDP + lc] = (lc < lr) ? __expf(acc[d] * 0.125f - rmv[d]) / rlv[d] : 0.f;
      }
    }
    __syncthreads();
    tri_solve_blocked(Sc, Ua, tid);
#pragma unroll
    for (int i2 = 0; i2 < 4; ++i2) {
      const int idx = tid + (i2 << 8);
      const int row = idx >> 4, c4 = (idx & 15) << 2;
      *reinterpret_cast<float4*>(Ub + ((size_t)bh * Tn + f * 64 + row) * 64 + c4) =
          *reinterpret_cast<const float4*>(Ua + row * LDU + c4);
    }
  } else {
#pragma unroll
    for (int i = 0; i < 4; ++i) {
      float4 v = {acc2[i][0], acc2[i][1], acc2[i][2], acc2[i][3]};
      *reinterpret_cast<float4*>(Ub + ((size_t)bh * Tn + f * 64 + 16 * wid + r) * 64 + 16 * i + 4 * g) = v;
    }
  }
}

// Momentum scan; 1 element/thread, writes fp16 M snapshots
__global__ __launch_bounds__(256) void mscan_kernel(
    const float* __restrict__ Ub, const float* __restrict__ kb,
    const float* __restrict__ theta, float* __restrict__ Mcarry,
    _Float16* __restrict__ Mbuf, int t0, int Tc) {
  const int gid = blockIdx.x * 256 + threadIdx.x;   // BHn*4096
  const int bh = gid >> 12, e = gid & 4095;
  const int dv = e >> 6, dk = e & 63;
  float M = Mcarry[gid];
  const float* Urow = Ub + (size_t)bh * Tn * 64;
  const float* krow = kb + (size_t)bh * Tn * 64;
  const float* th   = theta + (size_t)bh * Tn;
  for (int tl = 0; tl < Tc; ++tl) {
    const int t = t0 + tl;
    const float thv = th[t];
    const float g = Urow[(size_t)t * 64 + dv] * krow[(size_t)t * 64 + dk];
    M = thv * M + (1.f - thv) * g;
    Mbuf[((size_t)bh * Tc + tl) * 4096 + e] = (_Float16)M;
  }
  Mcarry[gid] = M;
}

// Newton-Schulz (6 iters), ONE WAVE per 64x64 matrix, register-resident.
// Symmetric m1/m2 (10 tiles) + exact identity-MFMA mirror fill (bit-identical).
__global__ __launch_bounds__(256, 4) void ns_kernel(_Float16* __restrict__ Mbuf) {
  __shared__ __align__(16) _Float16 Ms[4][64 * LH];
  const int tid  = threadIdx.x;
  const int wid  = tid >> 6, lane = tid & 63;
  const int r    = lane & 15, g = lane >> 4;
  _Float16* src = Mbuf + ((size_t)blockIdx.x * 4 + wid) * 4096;
  _Float16* lds = Ms[wid];
  const int lrow = (lane >> 3), lcol = (lane & 7) * 8;

  float ss = 0.f;
#pragma unroll
  for (int c = 0; c < 8; ++c) {
    const f16x8 h = *reinterpret_cast<const f16x8*>(src + c * 512 + lane * 8);
#pragma unroll
    for (int j = 0; j < 8; ++j) { const float f = (float)h[j]; ss += f * f; }
    *reinterpret_cast<f16x8*>(lds + (c * 8 + lrow) * LH + lcol) = h;
  }
#pragma unroll
  for (int off = 32; off > 0; off >>= 1) ss += __shfl_xor(ss, off, 64);
  const float inv = 1.f / (sqrtf(ss) + 1e-7f);

  f16x4 Xf[4][4];
#pragma unroll
  for (int i = 0; i < 4; ++i)
#pragma unroll
    for (int kc = 0; kc < 4; ++kc) {
      f16x4 h = *reinterpret_cast<const f16x4*>(lds + (i * 16 + r) * LH + kc * 16 + 4 * g);
#pragma unroll
      for (int d = 0; d < 4; ++d) h[d] = (_Float16)((float)h[d] * inv);
      Xf[i][kc] = h;
    }

  const f16x4 If = make_If(r, g);
  float Iw[4];
  Iw[0] = (float)If[0]; Iw[1] = (float)If[1]; Iw[2] = (float)If[2]; Iw[3] = (float)If[3];

  f16x4 Ff[4][4];
  f32x4 acc[4][4];

#pragma unroll 1
  for (int it = 0; it < 6; ++it) {
    const float ca = NS_Ac[it], cb = NS_Bc[it], cc = NS_Cc[it];
    // m1: acc[i][j] = (X X^T)(i,j), upper tiles only (symmetric)
#pragma unroll
    for (int i = 0; i < 4; ++i)
#pragma unroll
      for (int j = i; j < 4; ++j) {
        f32x4 a = {0.f, 0.f, 0.f, 0.f};
#pragma unroll
        for (int kc = 0; kc < 4; ++kc) a = mfma16(Xf[i][kc], Xf[j][kc], a);
        acc[i][j] = a;
      }
    // in-place transpose Xf := X^T frags (Xf dead after m1)
#pragma unroll
    for (int i = 0; i < 4; ++i) {
      {
        const f32x4 t = mfma16(Xf[i][i], If, (f32x4){0.f, 0.f, 0.f, 0.f});
        Xf[i][i] = cvt4(t);
      }
#pragma unroll
      for (int j = i + 1; j < 4; ++j) {
        const f32x4 t1 = mfma16(Xf[i][j], If, (f32x4){0.f, 0.f, 0.f, 0.f});
        const f32x4 t2 = mfma16(Xf[j][i], If, (f32x4){0.f, 0.f, 0.f, 0.f});
        Xf[j][i] = cvt4(t1);
        Xf[i][j] = cvt4(t2);
      }
    }
    // A frags: lower-left directly from acc, upper-right via exact transpose
#pragma unroll
    for (int i = 0; i < 4; ++i)
#pragma unroll
      for (int j = i; j < 4; ++j) Ff[j][i] = cvt4(acc[i][j]);
#pragma unroll
    for (int i = 0; i < 4; ++i)
#pragma unroll
      for (int j = i + 1; j < 4; ++j)
        Ff[i][j] = cvt4(mfma16(Ff[j][i], If, (f32x4){0.f, 0.f, 0.f, 0.f}));
    // m2: acc = cb A + cc A^2, upper tiles only; += ca I on diagonal
    const float bc = cb / cc;
#pragma unroll
    for (int i = 0; i < 4; ++i)
#pragma unroll
      for (int j = i; j < 4; ++j) {
        f32x4 a = acc[i][j];
        a[0] *= bc; a[1] *= bc; a[2] *= bc; a[3] *= bc;
#pragma unroll
        for (int kc = 0; kc < 4; ++kc) a = mfma16(Ff[i][kc], Ff[j][kc], a);
        a[0] *= cc; a[1] *= cc; a[2] *= cc; a[3] *= cc;
        acc[i][j] = a;
      }
#pragma unroll
    for (int i = 0; i < 4; ++i)
#pragma unroll
      for (int d = 0; d < 4; ++d) acc[i][i][d] = fmaf(ca, Iw[d], acc[i][i][d]);
    // Bm' frags: same symmetric fill
#pragma unroll
    for (int i = 0; i < 4; ++i)
#pragma unroll
      for (int j = i; j < 4; ++j) Ff[j][i] = cvt4(acc[i][j]);
#pragma unroll
    for (int i = 0; i < 4; ++i)
#pragma unroll
      for (int j = i + 1; j < 4; ++j)
        Ff[i][j] = cvt4(mfma16(Ff[j][i], If, (f32x4){0.f, 0.f, 0.f, 0.f}));
    // m3: acc = NT(X^T, Bm') -> X' frags (full)
#pragma unroll
    for (int i = 0; i < 4; ++i)
#pragma unroll
      for (int j = 0; j < 4; ++j) {
        f32x4 a = {0.f, 0.f, 0.f, 0.f};
#pragma unroll
        for (int kc = 0; kc < 4; ++kc) a = mfma16(Xf[i][kc], Ff[j][kc], a);
        acc[i][j] = a;
      }
#pragma unroll
    for (int i = 0; i < 4; ++i)
#pragma unroll
      for (int j = 0; j < 4; ++j) Xf[j][i] = cvt4(acc[i][j]);
  }

#pragma unroll
  for (int i = 0; i < 4; ++i)
#pragma unroll
    for (int kc = 0; kc < 4; ++kc)
      *reinterpret_cast<f16x4*>(lds + (i * 16 + r) * LH + kc * 16 + 4 * g) = Xf[i][kc];
#pragma unroll
  for (int c = 0; c < 8; ++c) {
    const f16x8 h = *reinterpret_cast<const f16x8*>(lds + (c * 8 + lrow) * LH + lcol);
    *reinterpret_cast<f16x8*>(src + c * 512 + lane * 8) = h;
  }
}

// P1: G_j = sum over 16-step subchunk of eta_s * Sp_s
__global__ __launch_bounds__(256) void gsum_kernel(
    const float* __restrict__ eta, const _Float16* __restrict__ Mbuf,
    float* __restrict__ Gbuf, int t0, int Tc) {
  const int j = blockIdx.x, bh = blockIdx.y, tid = threadIdx.x;
  const int nsub = Tc >> 4;
  float acc[16] = {};
#pragma unroll 1
  for (int i = 0; i < 16; ++i) {
    const int tl = j * 16 + i;
    const float ev = eta[(size_t)bh * Tn + t0 + tl];
    const _Float16* sp = Mbuf + ((size_t)bh * Tc + tl) * 4096;
    const f16x8 h0 = *reinterpret_cast<const f16x8*>(sp + tid * 8);
    const f16x8 h1 = *reinterpret_cast<const f16x8*>(sp + 2048 + tid * 8);
#pragma unroll
    for (int u = 0; u < 8; ++u) {
      acc[u]     += ev * (float)h0[u];
      acc[8 + u] += ev * (float)h1[u];
    }
  }
  float* g = Gbuf + ((size_t)bh * nsub + j) * 4096;
#pragma unroll
  for (int u = 0; u < 2; ++u) {
    float4 w0 = {acc[u*4], acc[u*4+1], acc[u*4+2], acc[u*4+3]};
    *reinterpret_cast<float4*>(g + tid * 8 + u * 4) = w0;
    float4 w1 = {acc[8+u*4], acc[8+u*4+1], acc[8+u*4+2], acc[8+u*4+3]};
    *reinterpret_cast<float4*>(g + 2048 + tid * 8 + u * 4) = w1;
  }
}

// P2: scan G over subchunks -> Sbase_j; updates Scarry
__global__ __launch_bounds__(256) void sbase_kernel(
    float* __restrict__ Scarry, const float* __restrict__ Gbuf,
    float* __restrict__ Sbase, int Tc) {
  const int gid = blockIdx.x * 256 + threadIdx.x;   // BHn*4096
  const int bh = gid >> 12, e = gid & 4095;
  const int nsub = Tc >> 4;
  float S = Scarry[gid];
  for (int j = 0; j < nsub; ++j) {
    const size_t idx = ((size_t)bh * nsub + j) * 4096 + e;
    Sbase[idx] = S;
    S += Gbuf[idx];
  }
  Scarry[gid] = S;
}

// P3: S in registers, 16 steps, shfl_xor reduce. Zero LDS/barriers.
__global__ __launch_bounds__(256) void outv2_kernel(
    const float* __restrict__ eta, const float* __restrict__ qb,
    const float* __restrict__ Sbase, const _Float16* __restrict__ Mbuf,
    float* __restrict__ ob, int t0, int Tc) {
  const int j = blockIdx.x, bh = blockIdx.y, tid = threadIdx.x;
  const int nsub = Tc >> 4;
  const int ty = tid >> 4, tx = tid & 15;
  const int dv0 = ty * 4, dk0 = tx * 4;
  float S[4][4];
  const float* sb = Sbase + ((size_t)bh * nsub + j) * 4096;
#pragma unroll
  for (int r = 0; r < 4; ++r) {
    const float4 v = *reinterpret_cast<const float4*>(sb + (dv0 + r) * 64 + dk0);
    S[r][0] = v.x; S[r][1] = v.y; S[r][2] = v.z; S[r][3] = v.w;
  }
#pragma unroll 1
  for (int i = 0; i < 16; ++i) {
    const int tl = j * 16 + i, t = t0 + tl;
    const float ev = eta[(size_t)bh * Tn + t];
    const float4 q4 = *reinterpret_cast<const float4*>(qb + ((size_t)bh * Tn + t) * 64 + dk0);
    const _Float16* sp = Mbuf + ((size_t)bh * Tc + tl) * 4096;
    float part[4];
#pragma unroll
    for (int r = 0; r < 4; ++r) {
      const f16x4 h = *reinterpret_cast<const f16x4*>(sp + (dv0 + r) * 64 + dk0);
      S[r][0] += ev * (float)h[0];
      S[r][1] += ev * (float)h[1];
      S[r][2] += ev * (float)h[2];
      S[r][3] += ev * (float)h[3];
      part[r] = S[r][0] * q4.x + S[r][1] * q4.y + S[r][2] * q4.z + S[r][3] * q4.w;
    }
#pragma unroll
    for (int m = 1; m < 16; m <<= 1)
#pragma unroll
      for (int r = 0; r < 4; ++r) part[r] += __shfl_xor(part[r], m, 64);
    if (tx == 0) {
      float4 o4 = {part[0], part[1], part[2], part[3]};
      *reinterpret_cast<float4*>(ob + ((size_t)bh * Tn + t) * 64 + dv0) = o4;
    }
  }
}

// init carries
__global__ __launch_bounds__(256) void init_carry_kernel(
    const float* __restrict__ S0, const float* __restrict__ M0,
    float* __restrict__ Scarry, float* __restrict__ Mcarry) {
  const int gid = blockIdx.x * 256 + threadIdx.x;
  const int h = (gid >> 12) & 7, e = gid & 4095;
  Scarry[gid] = S0[h * 4096 + e];
  Mcarry[gid] = M0[h * 4096 + e];
}

// final: out = o_flat @ Wo^T via fp16 MFMA
__global__ __launch_bounds__(256) void out_gemm_kernel(
    const float* __restrict__ ob, const float* __restrict__ Wo,
    float* __restrict__ out) {
  __shared__ __align__(16) _Float16 Af[64 * LH];
  __shared__ __align__(16) _Float16 Bf[64 * LH];
  const int tid = threadIdx.x;
  const int m0 = blockIdx.x * 64;
  const int n0 = blockIdx.y * 64;
  const int wid = tid >> 6, lane = tid & 63;
  const int r = lane & 15, g = lane >> 4;
  f32x4 acc[4] = {};
  for (int kt = 0; kt < Dn; kt += 64) {
    const int h = kt >> 6;
#pragma unroll
    for (int i = 0; i < 4; ++i) {
      const int idx = tid + (i << 8);
      const int row = idx >> 4, c4 = (idx & 15) << 2;
      const int m = m0 + row, b = m >> 10, t = m & 1023;
      const float4 v = *reinterpret_cast<const float4*>(
          ob + ((size_t)(b * Hn + h) * Tn + t) * 64 + c4);
      f16x4 hv;
      hv[0] = (_Float16)v.x; hv[1] = (_Float16)v.y; hv[2] = (_Float16)v.z; hv[3] = (_Float16)v.w;
      *reinterpret_cast<f16x4*>(Af + row * LH + c4) = hv;
    }
    stage_tile_h(Bf, Wo + (size_t)n0 * Dn + kt, Dn, tid);
    __syncthreads();
    f16x4 a4[4];
#pragma unroll
    for (int kc = 0; kc < 4; ++kc)
      a4[kc] = *reinterpret_cast<const f16x4*>(Af + (16 * wid + r) * LH + kc * 16 + 4 * g);
#pragma unroll
    for (int jb = 0; jb < 4; ++jb)
#pragma unroll
      for (int kc = 0; kc < 4; ++kc)
        acc[jb] = mfma16(a4[kc],
                         *reinterpret_cast<const f16x4*>(Bf + (16 * jb + r) * LH + kc * 16 + 4 * g),
                         acc[jb]);
    __syncthreads();
  }
#pragma unroll
  for (int jb = 0; jb < 4; ++jb)
#pragma unroll
    for (int d = 0; d < 4; ++d) {
      const int m = m0 + 16 * wid + 4 * g + d;
      const int n = n0 + 16 * jb + r;
      out[(size_t)m * Dn + n] = acc[jb][d];
    }
}

// ---------- host ----------

extern "C" void kernel_launch(void* const* d_in, const int* in_sizes, int n_in,
                              void* d_out, int out_size, void* d_ws, size_t ws_size,
                              hipStream_t stream) {
  (void)in_sizes; (void)n_in; (void)out_size;
  const float* x  = (const float*)d_in[0];
  const float* Wq = (const float*)d_in[1];
  const float* Wk = (const float*)d_in[2];
  const float* Wv = (const float*)d_in[3];
  const float* Ww = (const float*)d_in[4];
  const float* Wp = (const float*)d_in[5];
  const float* Wo = (const float*)d_in[6];
  const float* S0 = (const float*)d_in[7];
  const float* M0 = (const float*)d_in[8];
  float* out = (float*)d_out;
  float* ws  = (float*)d_ws;

  size_t off = 0;
  float* qb  = ws + off; off += (size_t)BHn * Tn * 64;
  float* kb  = ws + off; off += (size_t)BHn * Tn * 64;
  float* vb  = ws + off; off += (size_t)BHn * Tn * 64;
  float* wb  = ws + off; off += (size_t)BHn * Tn * 64;
  float* Ub  = ws + off; off += (size_t)BHn * Tn * 64;
  float* ob  = ws + off; off += (size_t)BHn * Tn * 64;
  float* eta   = ws + off; off += (size_t)BHn * Tn;
  float* theta = ws + off; off += (size_t)BHn * Tn;
  float* rowm  = ws + off; off += (size_t)BHn * Tn;
  float* rowl  = ws + off; off += (size_t)BHn * Tn;
  float* Mcarry = ws + off; off += (size_t)BHn * 4096;
  float* Scarry = ws + off; off += (size_t)BHn * 4096;

  const size_t avail0 = ws_size / sizeof(float) - off;
  int Tc = 256;
  while (Tc > 16 && (size_t)BHn * Tc * 2048 + 2 * (size_t)BHn * (Tc / 16) * 4096 > avail0)
    Tc >>= 1;
  const int nsub = Tc >> 4;

  float* Gbuf  = ws + off; off += (size_t)BHn * nsub * 4096;
  float* Sbase = ws + off; off += (size_t)BHn * nsub * 4096;
  _Float16* Mbuf = (_Float16*)(ws + off);

  hipLaunchKernelGGL(init_carry_kernel, dim3(512), dim3(256), 0, stream, S0, M0, Scarry, Mcarry);
  hipLaunchKernelGGL(proj4_kernel, dim3(64, 8, 4), dim3(256), 0, stream,
                     x, Wq, Wk, Wv, Ww, qb, kb, vb, wb);
  hipLaunchKernelGGL(wp_kernel, dim3(256), dim3(256), 0, stream, x, Wp, eta, theta);
  hipLaunchKernelGGL(rowstats_kernel, dim3(16, 32), dim3(256), 0, stream, wb, kb, rowm, rowl);
  hipLaunchKernelGGL(copyU_kernel, dim3(2048), dim3(256), 0, stream, vb, Ub);
  hipLaunchKernelGGL(solve_diag0_kernel, dim3(32), dim3(256), 0, stream,
                     wb, kb, vb, rowm, rowl, Ub);
  for (int ib = 0; ib < 15; ++ib) {
    hipLaunchKernelGGL(solve_step_kernel, dim3(15 - ib, 32), dim3(256), 0, stream,
                       wb, kb, rowm, rowl, Ub, ib);
  }

  for (int t0 = 0; t0 < Tn; t0 += Tc) {
    hipLaunchKernelGGL(mscan_kernel, dim3(512), dim3(256), 0, stream,
                       Ub, kb, theta, Mcarry, Mbuf, t0, Tc);
    hipLaunchKernelGGL(ns_kernel, dim3(BHn * Tc / 4), dim3(256), 0, stream, Mbuf);
    hipLaunchKernelGGL(gsum_kernel, dim3(nsub, BHn), dim3(256), 0, stream,
                       eta, Mbuf, Gbuf, t0, Tc);
    hipLaunchKernelGGL(sbase_kernel, dim3(512), dim3(256), 0, stream, Scarry, Gbuf, Sbase, Tc);
    hipLaunchKernelGGL(outv2_kernel, dim3(nsub, BHn), dim3(256), 0, stream,
                       eta, qb, Sbase, Mbuf, ob, t0, Tc);
  }

  hipLaunchKernelGGL(out_gemm_kernel, dim3(64, 8), dim3(256), 0, stream, ob, Wo, out);
}

// Round 9
// 1304.907 us; speedup vs baseline: 1.6337x; 1.0636x over previous
//
#include <hip/hip_runtime.h>
#include <hip/hip_bf16.h>
#include <math.h>

#define Bn 4
#define Tn 1024
#define Dn 512
#define Hn 8
#define BHn 32
#define LDP 65   // fp32 LDS stride (pad)
#define LDU 68   // fp32 LDS stride for Ua (16B-aligned rows)
#define LH 72    // fp16 LDS stride in halves

typedef _Float16 f16x8 __attribute__((ext_vector_type(8)));
typedef _Float16 f16x4 __attribute__((ext_vector_type(4)));
typedef float    f32x4 __attribute__((ext_vector_type(4)));

__constant__ float NS_Ac[6] = {3955.0f/1024.0f, 3735.0f/1024.0f, 3799.0f/1024.0f,
                               4019.0f/1024.0f, 2677.0f/1024.0f, 2172.0f/1024.0f};
__constant__ float NS_Bc[6] = {-8306.0f/1024.0f, -6681.0f/1024.0f, -6499.0f/1024.0f,
                               -6385.0f/1024.0f, -3029.0f/1024.0f, -1833.0f/1024.0f};
__constant__ float NS_Cc[6] = {5008.0f/1024.0f, 3463.0f/1024.0f, 3211.0f/1024.0f,
                               2906.0f/1024.0f, 1162.0f/1024.0f,  682.0f/1024.0f};

__device__ __forceinline__ f32x4 mfma16(f16x4 a, f16x4 b, f32x4 c) {
  return __builtin_amdgcn_mfma_f32_16x16x16f16(a, b, c, 0, 0, 0);
}
// K=32 MFMA. Operand convention: elements 0-3 = 16-col chunk (2c), k=4g+d;
// elements 4-7 = chunk (2c+1), k=4g+d. Valid because the k-sum is
// permutation-invariant when A and B share the same (g,j)->k mapping.
__device__ __forceinline__ f32x4 mfma32(f16x8 a, f16x8 b, f32x4 c) {
  return __builtin_amdgcn_mfma_f32_16x16x32_f16(a, b, c, 0, 0, 0);
}

__device__ __forceinline__ f16x4 cvt4(f32x4 a) {
  f16x4 h;
  h[0] = (_Float16)a[0]; h[1] = (_Float16)a[1];
  h[2] = (_Float16)a[2]; h[3] = (_Float16)a[3];
  return h;
}

__device__ __forceinline__ f16x8 pack8(f16x4 lo, f16x4 hi) {
  f16x8 o;
  o[0] = lo[0]; o[1] = lo[1]; o[2] = lo[2]; o[3] = lo[3];
  o[4] = hi[0]; o[5] = hi[1]; o[6] = hi[2]; o[7] = hi[3];
  return o;
}

__device__ __forceinline__ void set_half(f16x8& v, int h, f16x4 x) {
  if (h) { v[4] = x[0]; v[5] = x[1]; v[6] = x[2]; v[7] = x[3]; }
  else   { v[0] = x[0]; v[1] = x[1]; v[2] = x[2]; v[3] = x[3]; }
}

__device__ __forceinline__ f16x4 get_half(f16x8 v, int h) {
  f16x4 o;
  if (h) { o[0] = v[4]; o[1] = v[5]; o[2] = v[6]; o[3] = v[7]; }
  else   { o[0] = v[0]; o[1] = v[1]; o[2] = v[2]; o[3] = v[3]; }
  return o;
}

__device__ __forceinline__ f16x4 make_If(int r, int g) {
  const int dd = r - 4 * g;
  f16x4 If;
  If[0] = (dd == 0) ? (_Float16)1.f : (_Float16)0.f;
  If[1] = (dd == 1) ? (_Float16)1.f : (_Float16)0.f;
  If[2] = (dd == 2) ? (_Float16)1.f : (_Float16)0.f;
  If[3] = (dd == 3) ? (_Float16)1.f : (_Float16)0.f;
  return If;
}

// read f16x8 K=32 frag (row, 32-chunk c) from LDS tile [64][LH]
__device__ __forceinline__ f16x8 ld_frag8(const _Float16* lds, int row, int c, int g) {
  const f16x4 lo = *reinterpret_cast<const f16x4*>(lds + row * LH + (2 * c) * 16 + 4 * g);
  const f16x4 hi = *reinterpret_cast<const f16x4*>(lds + row * LH + (2 * c + 1) * 16 + 4 * g);
  return pack8(lo, hi);
}

// ---------- staging helpers ----------

__device__ __forceinline__ void stage_tile_h(_Float16* __restrict__ dst,
                                             const float* __restrict__ src,
                                             int srcStride, int tid) {
#pragma unroll
  for (int i = 0; i < 4; ++i) {
    const int idx = tid + (i << 8);
    const int row = idx >> 4;
    const int c4  = (idx & 15) << 2;
    const float4 v = *reinterpret_cast<const float4*>(src + (size_t)row * srcStride + c4);
    f16x4 h;
    h[0] = (_Float16)v.x; h[1] = (_Float16)v.y; h[2] = (_Float16)v.z; h[3] = (_Float16)v.w;
    *reinterpret_cast<f16x4*>(dst + row * LH + c4) = h;
  }
}

__device__ __forceinline__ void stage_tile_u(float* __restrict__ dst,
                                             const float* __restrict__ src, int tid) {
#pragma unroll
  for (int i = 0; i < 4; ++i) {
    const int idx = tid + (i << 8);
    const int row = idx >> 4;
    const int c4  = (idx & 15) << 2;
    *reinterpret_cast<float4*>(dst + row * LDU + c4) =
        *reinterpret_cast<const float4*>(src + (size_t)row * 64 + c4);
  }
}

// Blocked unit-lower-triangular solve
__device__ __forceinline__ void tri_solve_blocked(const float* __restrict__ Sc,
                                                  float* __restrict__ Ua, int tid) {
  const int dv = tid & 63;
  const int grp = tid >> 6;
#pragma unroll 1
  for (int db = 0; db < 4; ++db) {
    const int base = db * 16;
    if (grp == 0) {
#pragma unroll 1
      for (int rr = 1; rr < 16; ++rr) {
        float s = 0.f;
        for (int c = 0; c < rr; ++c)
          s = fmaf(Sc[(base + rr) * LDP + base + c], Ua[(base + c) * LDU + dv], s);
        Ua[(base + rr) * LDU + dv] -= s;
      }
    }
    __syncthreads();
    if (db < 3) {
      for (int r2 = base + 16 + grp; r2 < 64; r2 += 4) {
        float s = 0.f;
#pragma unroll
        for (int c = 0; c < 16; ++c)
          s = fmaf(Sc[r2 * LDP + base + c], Ua[(base + c) * LDU + dv], s);
        Ua[r2 * LDU + dv] -= s;
      }
    }
    __syncthreads();
  }
}

// ---------- kernels ----------

// q/k/v/w projections via fp16 MFMA (K=32)
__global__ __launch_bounds__(256) void proj4_kernel(
    const float* __restrict__ x,
    const float* __restrict__ W0, const float* __restrict__ W1,
    const float* __restrict__ W2, const float* __restrict__ W3,
    float* __restrict__ o0, float* __restrict__ o1,
    float* __restrict__ o2, float* __restrict__ o3) {
  __shared__ __align__(16) _Float16 Af[64 * LH];
  __shared__ __align__(16) _Float16 Bf[64 * LH];
  const float* W; float* outp;
  switch (blockIdx.z) {
    case 0:  W = W0; outp = o0; break;
    case 1:  W = W1; outp = o1; break;
    case 2:  W = W2; outp = o2; break;
    default: W = W3; outp = o3; break;
  }
  const int tid = threadIdx.x;
  const int m0 = blockIdx.x * 64;
  const int n0 = blockIdx.y * 64;
  const int wid = tid >> 6, lane = tid & 63;
  const int r = lane & 15, g = lane >> 4;
  f32x4 acc[4] = {};
  for (int kt = 0; kt < Dn; kt += 64) {
    stage_tile_h(Af, x + (size_t)m0 * Dn + kt, Dn, tid);
    stage_tile_h(Bf, W + (size_t)n0 * Dn + kt, Dn, tid);
    __syncthreads();
    f16x8 a8[2];
#pragma unroll
    for (int c = 0; c < 2; ++c) a8[c] = ld_frag8(Af, 16 * wid + r, c, g);
#pragma unroll
    for (int jb = 0; jb < 4; ++jb) {
#pragma unroll
      for (int c = 0; c < 2; ++c)
        acc[jb] = mfma32(a8[c], ld_frag8(Bf, 16 * jb + r, c, g), acc[jb]);
    }
    __syncthreads();
  }
#pragma unroll
  for (int jb = 0; jb < 4; ++jb)
#pragma unroll
    for (int d = 0; d < 4; ++d) {
      const int m = m0 + 16 * wid + 4 * g + d;
      const int n = n0 + 16 * jb + r;
      const int b = m >> 10, t = m & 1023, h = n >> 6, e = n & 63;
      outp[(((size_t)(b * Hn + h)) * Tn + t) * 64 + e] = acc[jb][d];
    }
}

// eta/theta projection
#define XSTR 516
__global__ __launch_bounds__(256) void wp_kernel(const float* __restrict__ x,
                                                 const float* __restrict__ Wp,
                                                 float* __restrict__ eta,
                                                 float* __restrict__ theta) {
  __shared__ float xs[16 * XSTR];
  __shared__ float wps[16 * XSTR];
  const int tid = threadIdx.x;
  const int r0 = blockIdx.x * 16;
#pragma unroll
  for (int i = 0; i < 8; ++i) {
    const int idx = tid + (i << 8);
    const int r = idx >> 7, c4 = (idx & 127) << 2;
    const float4 v = *reinterpret_cast<const float4*>(x + (size_t)(r0 + r) * Dn + c4);
    float* p = xs + r * XSTR + c4;
    p[0] = v.x; p[1] = v.y; p[2] = v.z; p[3] = v.w;
    const float4 wv = *reinterpret_cast<const float4*>(Wp + (size_t)r * Dn + c4);
    float* pw = wps + r * XSTR + c4;
    pw[0] = wv.x; pw[1] = wv.y; pw[2] = wv.z; pw[3] = wv.w;
  }
  __syncthreads();
  const int row = tid >> 4, col = tid & 15;
  float acc = 0.f;
#pragma unroll 8
  for (int k = 0; k < Dn; ++k) acc = fmaf(xs[row * XSTR + k], wps[col * XSTR + k], acc);
  const float sg = 1.f / (1.f + __expf(-acc));
  const int m = r0 + row, b = m >> 10, t = m & 1023, h = col >> 1;
  float* dst = (col & 1) ? theta : eta;
  dst[((size_t)(b * Hn + h)) * Tn + t] = sg;
}

// Per-row softmax stats via fp16 MFMA (K=32) + wave-parallel flash update.
__global__ __launch_bounds__(256) void rowstats_kernel(
    const float* __restrict__ wb, const float* __restrict__ kb,
    float* __restrict__ rowm, float* __restrict__ rowl) {
  __shared__ __align__(16) _Float16 Wh[64 * LH];
  __shared__ __align__(16) _Float16 Kh[64 * LH];
  const int tb = blockIdx.x, bh = blockIdx.y, t0 = tb * 64;
  const int tid = threadIdx.x, wid = tid >> 6, lane = tid & 63;
  const int r = lane & 15, g = lane >> 4;
  stage_tile_h(Wh, wb + ((size_t)bh * Tn + t0) * 64, 64, tid);
  float rm[4], rl[4];
#pragma unroll
  for (int d = 0; d < 4; ++d) { rm[d] = -INFINITY; rl[d] = 0.f; }
  __syncthreads();
  f16x8 wfr8[2];
#pragma unroll
  for (int c = 0; c < 2; ++c) wfr8[c] = ld_frag8(Wh, 16 * wid + r, c, g);
  for (int sb = 0; sb <= tb; ++sb) {
    __syncthreads();
    stage_tile_h(Kh, kb + ((size_t)bh * Tn + sb * 64) * 64, 64, tid);
    __syncthreads();
    float sv[4][4];
    float tmax[4] = {-INFINITY, -INFINITY, -INFINITY, -INFINITY};
#pragma unroll
    for (int jb = 0; jb < 4; ++jb) {
      f32x4 acc = {0.f, 0.f, 0.f, 0.f};
#pragma unroll
      for (int c = 0; c < 2; ++c)
        acc = mfma32(wfr8[c], ld_frag8(Kh, 16 * jb + r, c, g), acc);
      const int col = sb * 64 + 16 * jb + r;
#pragma unroll
      for (int d = 0; d < 4; ++d) {
        const int row = t0 + 16 * wid + 4 * g + d;
        const float s = (col < row) ? acc[d] * 0.125f : -INFINITY;
        sv[jb][d] = s;
        tmax[d] = fmaxf(tmax[d], s);
      }
    }
#pragma unroll
    for (int m = 1; m < 16; m <<= 1)
#pragma unroll
      for (int d = 0; d < 4; ++d) tmax[d] = fmaxf(tmax[d], __shfl_xor(tmax[d], m, 64));
#pragma unroll
    for (int d = 0; d < 4; ++d) {
      const float mnew  = fmaxf(rm[d], tmax[d]);
      const float msafe = (mnew == -INFINITY) ? 0.f : mnew;
      float s = __expf(sv[0][d] - msafe) + __expf(sv[1][d] - msafe) +
                __expf(sv[2][d] - msafe) + __expf(sv[3][d] - msafe);
#pragma unroll
      for (int m = 1; m < 16; m <<= 1) s += __shfl_xor(s, m, 64);
      const float scale = (rm[d] == -INFINITY) ? 0.f : __expf(rm[d] - msafe);
      rl[d] = rl[d] * scale + s;
      rm[d] = mnew;
    }
  }
  if (r == 0) {
#pragma unroll
    for (int d = 0; d < 4; ++d) {
      const int row = t0 + 16 * wid + 4 * g + d;
      rowm[(size_t)bh * Tn + row] = rm[d];
      rowl[(size_t)bh * Tn + row] = (rl[d] == 0.f) ? 1.f : rl[d];
    }
  }
}

// Ub := vb
__global__ __launch_bounds__(256) void copyU_kernel(const float* __restrict__ vb,
                                                    float* __restrict__ Ub) {
  const int gid = blockIdx.x * 256 + threadIdx.x;
  ((float4*)Ub)[gid] = ((const float4*)vb)[gid];
}

// diagonal solve of block 0 (K=16 path kept)
__global__ __launch_bounds__(256) void solve_diag0_kernel(
    const float* __restrict__ wb, const float* __restrict__ kb,
    const float* __restrict__ vb, const float* __restrict__ rowm,
    const float* __restrict__ rowl, float* __restrict__ Ub) {
  __shared__ __align__(16) _Float16 Wh[64 * LH];
  __shared__ __align__(16) _Float16 Kh[64 * LH];
  __shared__ float Sc[64 * LDP];
  __shared__ __align__(16) float Ua[64 * LDU];
  __shared__ float rmL[64], rlL[64];
  const int bh = blockIdx.x;
  const int tid = threadIdx.x, wid = tid >> 6, lane = tid & 63;
  const int r = lane & 15, g = lane >> 4;
  stage_tile_h(Wh, wb + (size_t)bh * Tn * 64, 64, tid);
  stage_tile_h(Kh, kb + (size_t)bh * Tn * 64, 64, tid);
  stage_tile_u(Ua, vb + (size_t)bh * Tn * 64, tid);
  if (tid < 64) { rmL[tid] = rowm[(size_t)bh * Tn + tid]; rlL[tid] = rowl[(size_t)bh * Tn + tid]; }
  __syncthreads();
  f16x4 wfr[4];
#pragma unroll
  for (int kc = 0; kc < 4; ++kc)
    wfr[kc] = *reinterpret_cast<const f16x4*>(Wh + (16 * wid + r) * LH + kc * 16 + 4 * g);
  float rmv[4], rlv[4];
#pragma unroll
  for (int d = 0; d < 4; ++d) {
    rmv[d] = rmL[16 * wid + 4 * g + d];
    rlv[d] = rlL[16 * wid + 4 * g + d];
  }
#pragma unroll
  for (int jb = 0; jb < 4; ++jb) {
    f32x4 acc = {0.f, 0.f, 0.f, 0.f};
#pragma unroll
    for (int kc = 0; kc < 4; ++kc)
      acc = mfma16(wfr[kc],
                   *reinterpret_cast<const f16x4*>(Kh + (16 * jb + r) * LH + kc * 16 + 4 * g),
                   acc);
#pragma unroll
    for (int d = 0; d < 4; ++d) {
      const int lr = 16 * wid + 4 * g + d, lc = 16 * jb + r;
      Sc[lr * LDP + lc] = (lc < lr) ? __expf(acc[d] * 0.125f - rmv[d]) / rlv[d] : 0.f;
    }
  }
  __syncthreads();
  tri_solve_blocked(Sc, Ua, tid);
#pragma unroll
  for (int i = 0; i < 4; ++i) {
    const int idx = tid + (i << 8);
    const int row = idx >> 4, c4 = (idx & 15) << 2;
    *reinterpret_cast<float4*>(Ub + ((size_t)bh * Tn + row) * 64 + c4) =
        *reinterpret_cast<const float4*>(Ua + row * LDU + c4);
  }
}

// step ib: U[f] -= P[f,ib] @ U[ib]; f==ib+1 also diag-solves (K=16 path kept)
__global__ __launch_bounds__(256) void solve_step_kernel(
    const float* __restrict__ wb, const float* __restrict__ kb,
    const float* __restrict__ rowm, const float* __restrict__ rowl,
    float* __restrict__ Ub, int ib) {
  __shared__ __align__(16) _Float16 Wh[64 * LH];
  __shared__ __align__(16) _Float16 Kh[64 * LH];
  __shared__ __align__(16) _Float16 UTh[64 * LH];
  __shared__ float Sc[64 * LDP];
  __shared__ __align__(16) float Ua[64 * LDU];
  __shared__ float rmL[64], rlL[64];
  const int f = ib + 1 + blockIdx.x, bh = blockIdx.y;
  const int tid = threadIdx.x, wid = tid >> 6, lane = tid & 63;
  const int r = lane & 15, g = lane >> 4;
  stage_tile_h(Wh, wb + ((size_t)bh * Tn + f * 64) * 64, 64, tid);
  stage_tile_h(Kh, kb + ((size_t)bh * Tn + ib * 64) * 64, 64, tid);
  {
    const float* src = Ub + ((size_t)bh * Tn + ib * 64) * 64;
#pragma unroll
    for (int i2 = 0; i2 < 4; ++i2) {
      const int idx = tid + (i2 << 8);
      const int row = idx >> 4, c4 = (idx & 15) << 2;
      const float4 v = *reinterpret_cast<const float4*>(src + (size_t)row * 64 + c4);
      UTh[(c4 + 0) * LH + row] = (_Float16)v.x;
      UTh[(c4 + 1) * LH + row] = (_Float16)v.y;
      UTh[(c4 + 2) * LH + row] = (_Float16)v.z;
      UTh[(c4 + 3) * LH + row] = (_Float16)v.w;
    }
  }
  if (tid < 64) {
    rmL[tid] = rowm[(size_t)bh * Tn + f * 64 + tid];
    rlL[tid] = rowl[(size_t)bh * Tn + f * 64 + tid];
  }
  __syncthreads();
  f16x4 wfr[4];
#pragma unroll
  for (int kc = 0; kc < 4; ++kc)
    wfr[kc] = *reinterpret_cast<const f16x4*>(Wh + (16 * wid + r) * LH + kc * 16 + 4 * g);
  float rmv[4], rlv[4];
#pragma unroll
  for (int d = 0; d < 4; ++d) {
    rmv[d] = rmL[16 * wid + 4 * g + d];
    rlv[d] = rlL[16 * wid + 4 * g + d];
  }
  const f16x4 If = make_If(r, g);
  f16x4 Pfr[4];
#pragma unroll
  for (int jb = 0; jb < 4; ++jb) {
    f32x4 acc = {0.f, 0.f, 0.f, 0.f};
#pragma unroll
    for (int kc = 0; kc < 4; ++kc)
      acc = mfma16(wfr[kc],
                   *reinterpret_cast<const f16x4*>(Kh + (16 * jb + r) * LH + kc * 16 + 4 * g),
                   acc);
    f16x4 pf;
#pragma unroll
    for (int d = 0; d < 4; ++d)
      pf[d] = (_Float16)(-__expf(acc[d] * 0.125f - rmv[d]) / rlv[d]);
    Pfr[jb] = cvt4(mfma16(pf, If, (f32x4){0.f, 0.f, 0.f, 0.f}));
  }
  const float* uf = Ub + ((size_t)bh * Tn + f * 64) * 64;
  f32x4 acc2[4];
#pragma unroll
  for (int i = 0; i < 4; ++i) {
    const float4 v = *reinterpret_cast<const float4*>(uf + (size_t)(16 * wid + r) * 64 + 16 * i + 4 * g);
    acc2[i][0] = v.x; acc2[i][1] = v.y; acc2[i][2] = v.z; acc2[i][3] = v.w;
#pragma unroll
    for (int kc = 0; kc < 4; ++kc)
      acc2[i] = mfma16(*reinterpret_cast<const f16x4*>(UTh + (16 * i + r) * LH + kc * 16 + 4 * g),
                       Pfr[kc], acc2[i]);
  }
  if (f == ib + 1) {
    __syncthreads();
    stage_tile_h(Kh, kb + ((size_t)bh * Tn + f * 64) * 64, 64, tid);
#pragma unroll
    for (int i = 0; i < 4; ++i) {
      float4 v = {acc2[i][0], acc2[i][1], acc2[i][2], acc2[i][3]};
      *reinterpret_cast<float4*>(Ua + (16 * wid + r) * LDU + 16 * i + 4 * g) = v;
    }
    __syncthreads();
#pragma unroll
    for (int jb = 0; jb < 4; ++jb) {
      f32x4 acc = {0.f, 0.f, 0.f, 0.f};
#pragma unroll
      for (int kc = 0; kc < 4; ++kc)
        acc = mfma16(wfr[kc],
                     *reinterpret_cast<const f16x4*>(Kh + (16 * jb + r) * LH + kc * 16 + 4 * g),
                     acc);
#pragma unroll
      for (int d = 0; d < 4; ++d) {
        const int lr = 16 * wid + 4 * g + d, lc = 16 * jb + r;
        Sc[lr * LDP + lc] = (lc < lr) ? __expf(acc[d] * 0.125f - rmv[d]) / rlv[d] : 0.f;
      }
    }
    __syncthreads();
    tri_solve_blocked(Sc, Ua, tid);
#pragma unroll
    for (int i2 = 0; i2 < 4; ++i2) {
      const int idx = tid + (i2 << 8);
      const int row = idx >> 4, c4 = (idx & 15) << 2;
      *reinterpret_cast<float4*>(Ub + ((size_t)bh * Tn + f * 64 + row) * 64 + c4) =
          *reinterpret_cast<const float4*>(Ua + row * LDU + c4);
    }
  } else {
#pragma unroll
    for (int i = 0; i < 4; ++i) {
      float4 v = {acc2[i][0], acc2[i][1], acc2[i][2], acc2[i][3]};
      *reinterpret_cast<float4*>(Ub + ((size_t)bh * Tn + f * 64 + 16 * wid + r) * 64 + 16 * i + 4 * g) = v;
    }
  }
}

// Momentum scan; 1 element/thread, writes fp16 M snapshots
__global__ __launch_bounds__(256) void mscan_kernel(
    const float* __restrict__ Ub, const float* __restrict__ kb,
    const float* __restrict__ theta, float* __restrict__ Mcarry,
    _Float16* __restrict__ Mbuf, int t0, int Tc) {
  const int gid = blockIdx.x * 256 + threadIdx.x;   // BHn*4096
  const int bh = gid >> 12, e = gid & 4095;
  const int dv = e >> 6, dk = e & 63;
  float M = Mcarry[gid];
  const float* Urow = Ub + (size_t)bh * Tn * 64;
  const float* krow = kb + (size_t)bh * Tn * 64;
  const float* th   = theta + (size_t)bh * Tn;
  for (int tl = 0; tl < Tc; ++tl) {
    const int t = t0 + tl;
    const float thv = th[t];
    const float g = Urow[(size_t)t * 64 + dv] * krow[(size_t)t * 64 + dk];
    M = thv * M + (1.f - thv) * g;
    Mbuf[((size_t)bh * Tc + tl) * 4096 + e] = (_Float16)M;
  }
  Mcarry[gid] = M;
}

// Newton-Schulz (6 iters), ONE WAVE per 64x64 matrix, register-resident, K=32 MFMA.
// Symmetric m1/m2 (10 tiles) + exact identity-MFMA mirror fill.
__global__ __launch_bounds__(256, 4) void ns_kernel(_Float16* __restrict__ Mbuf) {
  __shared__ __align__(16) _Float16 Ms[4][64 * LH];
  const int tid  = threadIdx.x;
  const int wid  = tid >> 6, lane = tid & 63;
  const int r    = lane & 15, g = lane >> 4;
  _Float16* src = Mbuf + ((size_t)blockIdx.x * 4 + wid) * 4096;
  _Float16* lds = Ms[wid];
  const int lrow = (lane >> 3), lcol = (lane & 7) * 8;

  float ss = 0.f;
#pragma unroll
  for (int c = 0; c < 8; ++c) {
    const f16x8 h = *reinterpret_cast<const f16x8*>(src + c * 512 + lane * 8);
#pragma unroll
    for (int j = 0; j < 8; ++j) { const float f = (float)h[j]; ss += f * f; }
    *reinterpret_cast<f16x8*>(lds + (c * 8 + lrow) * LH + lcol) = h;
  }
#pragma unroll
  for (int off = 32; off > 0; off >>= 1) ss += __shfl_xor(ss, off, 64);
  const float inv = 1.f / (sqrtf(ss) + 1e-7f);

  // Xf8[i][c]: 16x32 frag of tile-row i, 32-chunk c (halves = 16-col tiles 2c, 2c+1)
  f16x8 Xf8[4][2];
#pragma unroll
  for (int i = 0; i < 4; ++i)
#pragma unroll
    for (int c = 0; c < 2; ++c) {
      f16x8 h = ld_frag8(lds, i * 16 + r, c, g);
#pragma unroll
      for (int d = 0; d < 8; ++d) h[d] = (_Float16)((float)h[d] * inv);
      Xf8[i][c] = h;
    }

  const f16x4 If = make_If(r, g);
  f16x4 zero4;
  zero4[0] = (_Float16)0.f; zero4[1] = (_Float16)0.f;
  zero4[2] = (_Float16)0.f; zero4[3] = (_Float16)0.f;
  const f16x8 I8[2] = {pack8(If, zero4), pack8(zero4, If)};
  float Iw[4];
  Iw[0] = (float)If[0]; Iw[1] = (float)If[1]; Iw[2] = (float)If[2]; Iw[3] = (float)If[3];

  f16x8 Ff8[4][2];
  f32x4 acc[4][4];

#pragma unroll 1
  for (int it = 0; it < 6; ++it) {
    const float ca = NS_Ac[it], cb = NS_Bc[it], cc = NS_Cc[it];
    // m1: acc[i][j] = (X X^T)(i,j), upper tiles only (symmetric)
#pragma unroll
    for (int i = 0; i < 4; ++i)
#pragma unroll
      for (int j = i; j < 4; ++j) {
        f32x4 a = mfma32(Xf8[i][0], Xf8[j][0], (f32x4){0.f, 0.f, 0.f, 0.f});
        acc[i][j] = mfma32(Xf8[i][1], Xf8[j][1], a);
      }
    // in-place transpose at 16x16-tile granularity: new tile (a,b) = T(old (b,a))
#pragma unroll
    for (int i = 0; i < 4; ++i) {
      {
        const f16x4 t = cvt4(mfma32(Xf8[i][i >> 1], I8[i & 1], (f32x4){0.f, 0.f, 0.f, 0.f}));
        set_half(Xf8[i][i >> 1], i & 1, t);
      }
#pragma unroll
      for (int j = i + 1; j < 4; ++j) {
        const f16x4 t1 = cvt4(mfma32(Xf8[i][j >> 1], I8[j & 1], (f32x4){0.f, 0.f, 0.f, 0.f}));
        const f16x4 t2 = cvt4(mfma32(Xf8[j][i >> 1], I8[i & 1], (f32x4){0.f, 0.f, 0.f, 0.f}));
        set_half(Xf8[j][i >> 1], i & 1, t1);   // new (j,i) = T(old (i,j))
        set_half(Xf8[i][j >> 1], j & 1, t2);   // new (i,j) = T(old (j,i))
      }
    }
    // A frags: lower incl diag from acc (tile (j,i) = cvt4(acc[i][j])), mirrors via T
#pragma unroll
    for (int i = 0; i < 4; ++i)
#pragma unroll
      for (int j = i; j < 4; ++j) set_half(Ff8[j][i >> 1], i & 1, cvt4(acc[i][j]));
#pragma unroll
    for (int i = 0; i < 4; ++i)
#pragma unroll
      for (int j = i + 1; j < 4; ++j)
        set_half(Ff8[i][j >> 1], j & 1,
                 cvt4(mfma32(Ff8[j][i >> 1], I8[i & 1], (f32x4){0.f, 0.f, 0.f, 0.f})));
    // m2: acc = cb A + cc A^2, upper tiles only; += ca I on diagonal
    const float bc = cb / cc;
#pragma unroll
    for (int i = 0; i < 4; ++i)
#pragma unroll
      for (int j = i; j < 4; ++j) {
        f32x4 a = acc[i][j];
        a[0] *= bc; a[1] *= bc; a[2] *= bc; a[3] *= bc;
        a = mfma32(Ff8[i][0], Ff8[j][0], a);
        a = mfma32(Ff8[i][1], Ff8[j][1], a);
        a[0] *= cc; a[1] *= cc; a[2] *= cc; a[3] *= cc;
        acc[i][j] = a;
      }
#pragma unroll
    for (int i = 0; i < 4; ++i)
#pragma unroll
      for (int d = 0; d < 4; ++d) acc[i][i][d] = fmaf(ca, Iw[d], acc[i][i][d]);
    // Bm' frags: same symmetric fill
#pragma unroll
    for (int i = 0; i < 4; ++i)
#pragma unroll
      for (int j = i; j < 4; ++j) set_half(Ff8[j][i >> 1], i & 1, cvt4(acc[i][j]));
#pragma unroll
    for (int i = 0; i < 4; ++i)
#pragma unroll
      for (int j = i + 1; j < 4; ++j)
        set_half(Ff8[i][j >> 1], j & 1,
                 cvt4(mfma32(Ff8[j][i >> 1], I8[i & 1], (f32x4){0.f, 0.f, 0.f, 0.f})));
    // m3: acc = NT(X^T, Bm') -> X' frags: new tile (j,i) = cvt4(acc[i][j])
#pragma unroll
    for (int i = 0; i < 4; ++i)
#pragma unroll
      for (int j = 0; j < 4; ++j) {
        f32x4 a = mfma32(Xf8[i][0], Ff8[j][0], (f32x4){0.f, 0.f, 0.f, 0.f});
        acc[i][j] = mfma32(Xf8[i][1], Ff8[j][1], a);
      }
#pragma unroll
    for (int i = 0; i < 4; ++i)
#pragma unroll
      for (int j = 0; j < 4; ++j)
        set_half(Xf8[j][i >> 1], i & 1, cvt4(acc[i][j]));
  }

#pragma unroll
  for (int i = 0; i < 4; ++i)
#pragma unroll
    for (int c = 0; c < 2; ++c) {
      *reinterpret_cast<f16x4*>(lds + (i * 16 + r) * LH + (2 * c) * 16 + 4 * g) =
          get_half(Xf8[i][c], 0);
      *reinterpret_cast<f16x4*>(lds + (i * 16 + r) * LH + (2 * c + 1) * 16 + 4 * g) =
          get_half(Xf8[i][c], 1);
    }
#pragma unroll
  for (int c = 0; c < 8; ++c) {
    const f16x8 h = *reinterpret_cast<const f16x8*>(lds + (c * 8 + lrow) * LH + lcol);
    *reinterpret_cast<f16x8*>(src + c * 512 + lane * 8) = h;
  }
}

// P1: G_j = sum over 16-step subchunk of eta_s * Sp_s
__global__ __launch_bounds__(256) void gsum_kernel(
    const float* __restrict__ eta, const _Float16* __restrict__ Mbuf,
    float* __restrict__ Gbuf, int t0, int Tc) {
  const int j = blockIdx.x, bh = blockIdx.y, tid = threadIdx.x;
  const int nsub = Tc >> 4;
  float acc[16] = {};
#pragma unroll 1
  for (int i = 0; i < 16; ++i) {
    const int tl = j * 16 + i;
    const float ev = eta[(size_t)bh * Tn + t0 + tl];
    const _Float16* sp = Mbuf + ((size_t)bh * Tc + tl) * 4096;
    const f16x8 h0 = *reinterpret_cast<const f16x8*>(sp + tid * 8);
    const f16x8 h1 = *reinterpret_cast<const f16x8*>(sp + 2048 + tid * 8);
#pragma unroll
    for (int u = 0; u < 8; ++u) {
      acc[u]     += ev * (float)h0[u];
      acc[8 + u] += ev * (float)h1[u];
    }
  }
  float* g = Gbuf + ((size_t)bh * nsub + j) * 4096;
#pragma unroll
  for (int u = 0; u < 2; ++u) {
    float4 w0 = {acc[u*4], acc[u*4+1], acc[u*4+2], acc[u*4+3]};
    *reinterpret_cast<float4*>(g + tid * 8 + u * 4) = w0;
    float4 w1 = {acc[8+u*4], acc[8+u*4+1], acc[8+u*4+2], acc[8+u*4+3]};
    *reinterpret_cast<float4*>(g + 2048 + tid * 8 + u * 4) = w1;
  }
}

// P2: scan G over subchunks -> Sbase_j; updates Scarry
__global__ __launch_bounds__(256) void sbase_kernel(
    float* __restrict__ Scarry, const float* __restrict__ Gbuf,
    float* __restrict__ Sbase, int Tc) {
  const int gid = blockIdx.x * 256 + threadIdx.x;   // BHn*4096
  const int bh = gid >> 12, e = gid & 4095;
  const int nsub = Tc >> 4;
  float S = Scarry[gid];
  for (int j = 0; j < nsub; ++j) {
    const size_t idx = ((size_t)bh * nsub + j) * 4096 + e;
    Sbase[idx] = S;
    S += Gbuf[idx];
  }
  Scarry[gid] = S;
}

// P3: S in registers, 16 steps, shfl_xor reduce. Zero LDS/barriers.
__global__ __launch_bounds__(256) void outv2_kernel(
    const float* __restrict__ eta, const float* __restrict__ qb,
    const float* __restrict__ Sbase, const _Float16* __restrict__ Mbuf,
    float* __restrict__ ob, int t0, int Tc) {
  const int j = blockIdx.x, bh = blockIdx.y, tid = threadIdx.x;
  const int nsub = Tc >> 4;
  const int ty = tid >> 4, tx = tid & 15;
  const int dv0 = ty * 4, dk0 = tx * 4;
  float S[4][4];
  const float* sb = Sbase + ((size_t)bh * nsub + j) * 4096;
#pragma unroll
  for (int r = 0; r < 4; ++r) {
    const float4 v = *reinterpret_cast<const float4*>(sb + (dv0 + r) * 64 + dk0);
    S[r][0] = v.x; S[r][1] = v.y; S[r][2] = v.z; S[r][3] = v.w;
  }
#pragma unroll 1
  for (int i = 0; i < 16; ++i) {
    const int tl = j * 16 + i, t = t0 + tl;
    const float ev = eta[(size_t)bh * Tn + t];
    const float4 q4 = *reinterpret_cast<const float4*>(qb + ((size_t)bh * Tn + t) * 64 + dk0);
    const _Float16* sp = Mbuf + ((size_t)bh * Tc + tl) * 4096;
    float part[4];
#pragma unroll
    for (int r = 0; r < 4; ++r) {
      const f16x4 h = *reinterpret_cast<const f16x4*>(sp + (dv0 + r) * 64 + dk0);
      S[r][0] += ev * (float)h[0];
      S[r][1] += ev * (float)h[1];
      S[r][2] += ev * (float)h[2];
      S[r][3] += ev * (float)h[3];
      part[r] = S[r][0] * q4.x + S[r][1] * q4.y + S[r][2] * q4.z + S[r][3] * q4.w;
    }
#pragma unroll
    for (int m = 1; m < 16; m <<= 1)
#pragma unroll
      for (int r = 0; r < 4; ++r) part[r] += __shfl_xor(part[r], m, 64);
    if (tx == 0) {
      float4 o4 = {part[0], part[1], part[2], part[3]};
      *reinterpret_cast<float4*>(ob + ((size_t)bh * Tn + t) * 64 + dv0) = o4;
    }
  }
}

// init carries
__global__ __launch_bounds__(256) void init_carry_kernel(
    const float* __restrict__ S0, const float* __restrict__ M0,
    float* __restrict__ Scarry, float* __restrict__ Mcarry) {
  const int gid = blockIdx.x * 256 + threadIdx.x;
  const int h = (gid >> 12) & 7, e = gid & 4095;
  Scarry[gid] = S0[h * 4096 + e];
  Mcarry[gid] = M0[h * 4096 + e];
}

// final: out = o_flat @ Wo^T via fp16 MFMA (K=32)
__global__ __launch_bounds__(256) void out_gemm_kernel(
    const float* __restrict__ ob, const float* __restrict__ Wo,
    float* __restrict__ out) {
  __shared__ __align__(16) _Float16 Af[64 * LH];
  __shared__ __align__(16) _Float16 Bf[64 * LH];
  const int tid = threadIdx.x;
  const int m0 = blockIdx.x * 64;
  const int n0 = blockIdx.y * 64;
  const int wid = tid >> 6, lane = tid & 63;
  const int r = lane & 15, g = lane >> 4;
  f32x4 acc[4] = {};
  for (int kt = 0; kt < Dn; kt += 64) {
    const int h = kt >> 6;
#pragma unroll
    for (int i = 0; i < 4; ++i) {
      const int idx = tid + (i << 8);
      const int row = idx >> 4, c4 = (idx & 15) << 2;
      const int m = m0 + row, b = m >> 10, t = m & 1023;
      const float4 v = *reinterpret_cast<const float4*>(
          ob + ((size_t)(b * Hn + h) * Tn + t) * 64 + c4);
      f16x4 hv;
      hv[0] = (_Float16)v.x; hv[1] = (_Float16)v.y; hv[2] = (_Float16)v.z; hv[3] = (_Float16)v.w;
      *reinterpret_cast<f16x4*>(Af + row * LH + c4) = hv;
    }
    stage_tile_h(Bf, Wo + (size_t)n0 * Dn + kt, Dn, tid);
    __syncthreads();
    f16x8 a8[2];
#pragma unroll
    for (int c = 0; c < 2; ++c) a8[c] = ld_frag8(Af, 16 * wid + r, c, g);
#pragma unroll
    for (int jb = 0; jb < 4; ++jb) {
#pragma unroll
      for (int c = 0; c < 2; ++c)
        acc[jb] = mfma32(a8[c], ld_frag8(Bf, 16 * jb + r, c, g), acc[jb]);
    }
    __syncthreads();
  }
#pragma unroll
  for (int jb = 0; jb < 4; ++jb)
#pragma unroll
    for (int d = 0; d < 4; ++d) {
      const int m = m0 + 16 * wid + 4 * g + d;
      const int n = n0 + 16 * jb + r;
      out[(size_t)m * Dn + n] = acc[jb][d];
    }
}

// ---------- host ----------

extern "C" void kernel_launch(void* const* d_in, const int* in_sizes, int n_in,
                              void* d_out, int out_size, void* d_ws, size_t ws_size,
                              hipStream_t stream) {
  (void)in_sizes; (void)n_in; (void)out_size;
  const float* x  = (const float*)d_in[0];
  const float* Wq = (const float*)d_in[1];
  const float* Wk = (const float*)d_in[2];
  const float* Wv = (const float*)d_in[3];
  const float* Ww = (const float*)d_in[4];
  const float* Wp = (const float*)d_in[5];
  const float* Wo = (const float*)d_in[6];
  const float* S0 = (const float*)d_in[7];
  const float* M0 = (const float*)d_in[8];
  float* out = (float*)d_out;
  float* ws  = (float*)d_ws;

  size_t off = 0;
  float* qb  = ws + off; off += (size_t)BHn * Tn * 64;
  float* kb  = ws + off; off += (size_t)BHn * Tn * 64;
  float* vb  = ws + off; off += (size_t)BHn * Tn * 64;
  float* wb  = ws + off; off += (size_t)BHn * Tn * 64;
  float* Ub  = ws + off; off += (size_t)BHn * Tn * 64;
  float* ob  = ws + off; off += (size_t)BHn * Tn * 64;
  float* eta   = ws + off; off += (size_t)BHn * Tn;
  float* theta = ws + off; off += (size_t)BHn * Tn;
  float* rowm  = ws + off; off += (size_t)BHn * Tn;
  float* rowl  = ws + off; off += (size_t)BHn * Tn;
  float* Mcarry = ws + off; off += (size_t)BHn * 4096;
  float* Scarry = ws + off; off += (size_t)BHn * 4096;

  const size_t avail0 = ws_size / sizeof(float) - off;
  int Tc = 256;
  while (Tc > 16 && (size_t)BHn * Tc * 2048 + 2 * (size_t)BHn * (Tc / 16) * 4096 > avail0)
    Tc >>= 1;
  const int nsub = Tc >> 4;

  float* Gbuf  = ws + off; off += (size_t)BHn * nsub * 4096;
  float* Sbase = ws + off; off += (size_t)BHn * nsub * 4096;
  _Float16* Mbuf = (_Float16*)(ws + off);

  hipLaunchKernelGGL(init_carry_kernel, dim3(512), dim3(256), 0, stream, S0, M0, Scarry, Mcarry);
  hipLaunchKernelGGL(proj4_kernel, dim3(64, 8, 4), dim3(256), 0, stream,
                     x, Wq, Wk, Wv, Ww, qb, kb, vb, wb);
  hipLaunchKernelGGL(wp_kernel, dim3(256), dim3(256), 0, stream, x, Wp, eta, theta);
  hipLaunchKernelGGL(rowstats_kernel, dim3(16, 32), dim3(256), 0, stream, wb, kb, rowm, rowl);
  hipLaunchKernelGGL(copyU_kernel, dim3(2048), dim3(256), 0, stream, vb, Ub);
  hipLaunchKernelGGL(solve_diag0_kernel, dim3(32), dim3(256), 0, stream,
                     wb, kb, vb, rowm, rowl, Ub);
  for (int ib = 0; ib < 15; ++ib) {
    hipLaunchKernelGGL(solve_step_kernel, dim3(15 - ib, 32), dim3(256), 0, stream,
                       wb, kb, rowm, rowl, Ub, ib);
  }

  for (int t0 = 0; t0 < Tn; t0 += Tc) {
    hipLaunchKernelGGL(mscan_kernel, dim3(512), dim3(256), 0, stream,
                       Ub, kb, theta, Mcarry, Mbuf, t0, Tc);
    hipLaunchKernelGGL(ns_kernel, dim3(BHn * Tc / 4), dim3(256), 0, stream, Mbuf);
    hipLaunchKernelGGL(gsum_kernel, dim3(nsub, BHn), dim3(256), 0, stream,
                       eta, Mbuf, Gbuf, t0, Tc);
    hipLaunchKernelGGL(sbase_kernel, dim3(512), dim3(256), 0, stream, Scarry, Gbuf, Sbase, Tc);
    hipLaunchKernelGGL(outv2_kernel, dim3(nsub, BHn), dim3(256), 0, stream,
                       eta, qb, Sbase, Mbuf, ob, t0, Tc);
  }

  hipLaunchKernelGGL(out_gemm_kernel, dim3(64, 8), dim3(256), 0, stream, ob, Wo, out);
}